// Round 2
// baseline (11954.153 us; speedup 1.0000x reference)
//
#include <hip/hip_runtime.h>
#include <hip/hip_bf16.h>

#define NUSER 100000
#define NITEM 50000
#define NNODE 150000
#define DIM 128
#define NB 3
#define NL 2
#define BN_EPS 1e-5f

typedef unsigned short u16;

__device__ __forceinline__ float b2f(u16 u) {
    return __uint_as_float(((unsigned)u) << 16);
}
__device__ __forceinline__ u16 f2b(float f) {
    unsigned x = __float_as_uint(f);
    unsigned r = (x + 0x7fffu + ((x >> 16) & 1u)) >> 16;
    return (u16)r;
}

// ---------------- edge preprocessing ----------------

__global__ __launch_bounds__(256) void count_edges(const int* __restrict__ ei,
                                                   const int* __restrict__ et, int E,
                                                   int* __restrict__ cnt, int* __restrict__ small) {
    int t = blockIdx.x * 256 + threadIdx.x;
    int myb = -1, dst = 0;
    if (t < E) { myb = et[t]; dst = ei[E + t]; }
    if (t < E) atomicAdd(&cnt[myb * NNODE + dst], 1);
    int lane = threadIdx.x & 63;
    for (int bb = 0; bb < NB; ++bb) {
        unsigned long long mask = __ballot(myb == bb);
        if (mask == 0ull) continue;
        int leader = __ffsll(mask) - 1;
        if (lane == leader) atomicAdd(&small[bb], __popcll(mask));
    }
}

__global__ void compute_offs(int* small) {
    small[3] = 0;
    small[4] = small[0];
    small[5] = small[0] + small[1];
    small[6] = small[3];
    small[7] = small[4];
    small[8] = small[5];
}

__global__ __launch_bounds__(256) void scatter_edges(const int* __restrict__ ei,
                                                     const int* __restrict__ et, int E,
                                                     int* __restrict__ small, int* __restrict__ elist) {
    int t = blockIdx.x * 256 + threadIdx.x;
    int myb = -1, src = 0, dst = 0;
    if (t < E) { myb = et[t]; src = ei[t]; dst = ei[E + t]; }
    int lane = threadIdx.x & 63;
    for (int bb = 0; bb < NB; ++bb) {
        unsigned long long mask = __ballot(myb == bb);
        if (mask == 0ull) continue;
        int leader = __ffsll(mask) - 1;
        int c = __popcll(mask);
        int base = 0;
        if (lane == leader) base = atomicAdd(&small[6 + bb], c);
        base = __shfl(base, leader);
        if (myb == bb) {
            int prefix = __popcll(mask & ((1ull << lane) - 1ull));
            int p = base + prefix;
            elist[2 * p] = src;
            elist[2 * p + 1] = dst;
        }
    }
}

__global__ __launch_bounds__(256) void make_inv_denom(int* __restrict__ cnt, int n3) {
    int t = blockIdx.x * 256 + threadIdx.x;
    if (t >= n3) return;
    int c = cnt[t];
    float v = 1.0f / (float)(c > 1 ? c : 1);
    ((float*)cnt)[t] = v;
}

// ---------------- aggregation: agg[dst] += h[src] * invd[dst] ----------------

__global__ __launch_bounds__(256) void aggregate(const void* __restrict__ hv, int in_bf16,
                                                 float* __restrict__ agg,
                                                 const int* __restrict__ elist,
                                                 const int* __restrict__ small,
                                                 const float* __restrict__ invd, int b) {
    int ne = small[b];
    int off = small[3 + b];
    int lane = threadIdx.x & 31;
    int hw = (blockIdx.x * 256 + threadIdx.x) >> 5;
    int stride = (gridDim.x * 256) >> 5;
    for (int e = hw; e < ne; e += stride) {
        int src = elist[2 * (off + e)];
        int dst = elist[2 * (off + e) + 1];
        float s = invd[dst];
        float v0, v1, v2, v3;
        if (in_bf16) {
            ushort4 u = *(const ushort4*)((const u16*)hv + (size_t)src * DIM + lane * 4);
            v0 = b2f(u.x); v1 = b2f(u.y); v2 = b2f(u.z); v3 = b2f(u.w);
        } else {
            float4 f = *(const float4*)((const float*)hv + (size_t)src * DIM + lane * 4);
            v0 = f.x; v1 = f.y; v2 = f.z; v3 = f.w;
        }
        float* a = agg + (size_t)dst * DIM + lane * 4;
        atomicAdd(a + 0, v0 * s);
        atomicAdd(a + 1, v1 * s);
        atomicAdd(a + 2, v2 * s);
        atomicAdd(a + 3, v3 * s);
    }
}

// ---------------- unified GEMM: C = A1@W1 + bias [+ A2@W2], 64x128 tile ----------------
// flags: 1=relu, 2=dual, 4=stats, 8=A1 bf16, 16=A2 bf16, 32=C bf16
// LDS: 32KB W-chunk + 1KB stats. A read via broadcast global loads (L1-resident).
// In-place safe for C aliasing A1 or A2 (blocks own disjoint row ranges; all
// reads of a block's rows precede its stores).

__global__ __launch_bounds__(512) void gemm64(const void* A1v, const float* __restrict__ W1,
                                              const float* __restrict__ bias,
                                              const void* A2v, const float* __restrict__ W2,
                                              void* Cv, int M, float* __restrict__ stats,
                                              int flags) {
    __shared__ float wc[64 * DIM];
    __shared__ float ssum[DIM];
    __shared__ float ssq[DIM];
    const int tid = threadIdx.x;
    if ((flags & 4) && tid < DIM) { ssum[tid] = 0.f; ssq[tid] = 0.f; }
    const int c4 = (tid & 31) * 4;
    const int r = tid >> 5;          // 0..15
    const int KT = (flags & 2) ? 256 : 128;
    float rs0 = 0, rs1 = 0, rs2 = 0, rs3 = 0;
    float rq0 = 0, rq1 = 0, rq2 = 0, rq3 = 0;
    const int tiles = (M + 63) >> 6;
    for (int tile = blockIdx.x; tile < tiles; tile += gridDim.x) {
        const int r0 = tile << 6;
        float acc[4][4];
#pragma unroll
        for (int i = 0; i < 4; ++i)
#pragma unroll
            for (int j = 0; j < 4; ++j) acc[i][j] = 0.f;
        int row[4];
#pragma unroll
        for (int i = 0; i < 4; ++i) row[i] = r0 + r + 16 * i;
        for (int ch = 0; ch < KT; ch += 64) {
            const float* Wsrc = (ch < 128) ? W1 : W2;
            const int kb = ch & 127;
            __syncthreads();
            for (int i = tid; i < 64 * DIM / 4; i += 512)
                ((float4*)wc)[i] = ((const float4*)(Wsrc + (size_t)kb * DIM))[i];
            __syncthreads();
            const void* Av = (ch < 128) ? A1v : A2v;
            const bool abf = (ch < 128) ? ((flags & 8) != 0) : ((flags & 16) != 0);
            for (int k4 = 0; k4 < 64; k4 += 4) {
                float a[4][4];
#pragma unroll
                for (int i = 0; i < 4; ++i) {
                    if (row[i] < M) {
                        if (abf) {
                            ushort4 u = *(const ushort4*)((const u16*)Av + (size_t)row[i] * DIM + kb + k4);
                            a[i][0] = b2f(u.x); a[i][1] = b2f(u.y);
                            a[i][2] = b2f(u.z); a[i][3] = b2f(u.w);
                        } else {
                            float4 v = *(const float4*)((const float*)Av + (size_t)row[i] * DIM + kb + k4);
                            a[i][0] = v.x; a[i][1] = v.y; a[i][2] = v.z; a[i][3] = v.w;
                        }
                    } else {
                        a[i][0] = a[i][1] = a[i][2] = a[i][3] = 0.f;
                    }
                }
#pragma unroll
                for (int j = 0; j < 4; ++j) {
                    const float4 w = *(const float4*)&wc[(k4 + j) * DIM + c4];
#pragma unroll
                    for (int i = 0; i < 4; ++i) {
                        acc[i][0] = fmaf(a[i][j], w.x, acc[i][0]);
                        acc[i][1] = fmaf(a[i][j], w.y, acc[i][1]);
                        acc[i][2] = fmaf(a[i][j], w.z, acc[i][2]);
                        acc[i][3] = fmaf(a[i][j], w.w, acc[i][3]);
                    }
                }
            }
        }
        const float4 bb = *(const float4*)&bias[c4];
#pragma unroll
        for (int i = 0; i < 4; ++i) {
            if (row[i] >= M) continue;
            float o0 = acc[i][0] + bb.x, o1 = acc[i][1] + bb.y;
            float o2 = acc[i][2] + bb.z, o3 = acc[i][3] + bb.w;
            if (flags & 1) {
                o0 = fmaxf(o0, 0.f); o1 = fmaxf(o1, 0.f);
                o2 = fmaxf(o2, 0.f); o3 = fmaxf(o3, 0.f);
            }
            if (flags & 4) {
                rs0 += o0; rs1 += o1; rs2 += o2; rs3 += o3;
                rq0 += o0 * o0; rq1 += o1 * o1; rq2 += o2 * o2; rq3 += o3 * o3;
            }
            if (flags & 32) {
                ushort4 u;
                u.x = f2b(o0); u.y = f2b(o1); u.z = f2b(o2); u.w = f2b(o3);
                *(ushort4*)((u16*)Cv + (size_t)row[i] * DIM + c4) = u;
            } else {
                float4 o;
                o.x = o0; o.y = o1; o.z = o2; o.w = o3;
                *(float4*)((float*)Cv + (size_t)row[i] * DIM + c4) = o;
            }
        }
    }
    if (flags & 4) {
        __syncthreads();
        atomicAdd(&ssum[c4 + 0], rs0); atomicAdd(&ssum[c4 + 1], rs1);
        atomicAdd(&ssum[c4 + 2], rs2); atomicAdd(&ssum[c4 + 3], rs3);
        atomicAdd(&ssq[c4 + 0], rq0);  atomicAdd(&ssq[c4 + 1], rq1);
        atomicAdd(&ssq[c4 + 2], rq2);  atomicAdd(&ssq[c4 + 3], rq3);
        __syncthreads();
        if (tid < DIM) {
            atomicAdd(&stats[tid], ssum[tid]);
            atomicAdd(&stats[DIM + tid], ssq[tid]);
        }
    }
}

// ---------------- BatchNorm apply ----------------
// relu for l=0; for l=1: add bf16 residual and store bf16 to stack.

__global__ __launch_bounds__(256) void bn_apply(float* __restrict__ h, const float* __restrict__ stats,
                                                const float* __restrict__ gamma, const float* __restrict__ beta,
                                                const u16* __restrict__ addx, u16* __restrict__ outb,
                                                int relu) {
    int t = blockIdx.x * 256 + threadIdx.x;
    if (t >= NNODE * 32) return;
    int n = t >> 5;
    int d = (t & 31) * 4;
    const float invN = 1.0f / (float)NNODE;
    float4 s = *(const float4*)&stats[d];
    float4 sq = *(const float4*)&stats[DIM + d];
    float4 g = *(const float4*)&gamma[d];
    float4 be = *(const float4*)&beta[d];
    float mx = s.x * invN, my = s.y * invN, mz = s.z * invN, mw = s.w * invN;
    float cx = g.x * rsqrtf(fmaxf(sq.x * invN - mx * mx, 0.f) + BN_EPS);
    float cy = g.y * rsqrtf(fmaxf(sq.y * invN - my * my, 0.f) + BN_EPS);
    float cz = g.z * rsqrtf(fmaxf(sq.z * invN - mz * mz, 0.f) + BN_EPS);
    float cw = g.w * rsqrtf(fmaxf(sq.w * invN - mw * mw, 0.f) + BN_EPS);
    float4 v = *(float4*)(h + (size_t)n * DIM + d);
    v.x = (v.x - mx) * cx + be.x;
    v.y = (v.y - my) * cy + be.y;
    v.z = (v.z - mz) * cz + be.z;
    v.w = (v.w - mw) * cw + be.w;
    if (relu) {
        v.x = fmaxf(v.x, 0.f); v.y = fmaxf(v.y, 0.f);
        v.z = fmaxf(v.z, 0.f); v.w = fmaxf(v.w, 0.f);
    }
    if (addx) {
        ushort4 u = *(const ushort4*)(addx + (size_t)n * DIM + d);
        v.x += b2f(u.x); v.y += b2f(u.y); v.z += b2f(u.z); v.w += b2f(u.w);
    }
    if (outb) {
        ushort4 o;
        o.x = f2b(v.x); o.y = f2b(v.y); o.z = f2b(v.z); o.w = f2b(v.w);
        *(ushort4*)(outb + (size_t)n * DIM + d) = o;
    } else {
        *(float4*)(h + (size_t)n * DIM + d) = v;
    }
}

// ---------------- attention helpers ----------------

__global__ __launch_bounds__(256) void rowdot(const float* __restrict__ Q, const float* __restrict__ K,
                                              float* __restrict__ logits, int b) {
    int t = blockIdx.x * 256 + threadIdx.x;
    int n = t >> 5;
    int lane = t & 31;
    if (n >= NNODE) return;
    const float4 q = *(const float4*)(Q + (size_t)n * DIM + lane * 4);
    const float4 k = *(const float4*)(K + (size_t)n * DIM + lane * 4);
    float p = q.x * k.x + q.y * k.y + q.z * k.z + q.w * k.w;
    p += __shfl_down(p, 16);
    p += __shfl_down(p, 8);
    p += __shfl_down(p, 4);
    p += __shfl_down(p, 2);
    p += __shfl_down(p, 1);
    if (lane == 0) logits[n * NB + b] = p;
}

__global__ __launch_bounds__(256) void softmax_fuse(const float* __restrict__ logits,
                                                    const u16* __restrict__ stk,
                                                    float* __restrict__ out) {
    int t = blockIdx.x * 256 + threadIdx.x;
    if (t >= NNODE * 32) return;
    int n = t >> 5;
    int d = (t & 31) * 4;
    float l0 = logits[n * NB + 0];
    float l1 = logits[n * NB + 1];
    float l2 = logits[n * NB + 2];
    float m = fmaxf(l0, fmaxf(l1, l2));
    float e0 = expf(l0 - m), e1 = expf(l1 - m), e2 = expf(l2 - m);
    float inv = 1.0f / (e0 + e1 + e2);
    float w0 = e0 * inv, w1 = e1 * inv, w2 = e2 * inv;
    size_t base = (size_t)n * DIM + d;
    ushort4 u0 = *(const ushort4*)(stk + base);
    ushort4 u1 = *(const ushort4*)(stk + (size_t)NNODE * DIM + base);
    ushort4 u2 = *(const ushort4*)(stk + (size_t)2 * NNODE * DIM + base);
    float4 o;
    o.x = w0 * b2f(u0.x) + w1 * b2f(u1.x) + w2 * b2f(u2.x);
    o.y = w0 * b2f(u0.y) + w1 * b2f(u1.y) + w2 * b2f(u2.y);
    o.z = w0 * b2f(u0.z) + w1 * b2f(u1.z) + w2 * b2f(u2.z);
    o.w = w0 * b2f(u0.w) + w1 * b2f(u1.w) + w2 * b2f(u2.w);
    *(float4*)(out + base) = o;
}

// ---------------- launch ----------------

extern "C" void kernel_launch(void* const* d_in, const int* in_sizes, int n_in,
                              void* d_out, int out_size, void* d_ws, size_t ws_size,
                              hipStream_t stream) {
    const int* edge_index    = (const int*)d_in[0];
    const int* edge_type     = (const int*)d_in[1];
    const float* item_feats  = (const float*)d_in[2];
    const float* user_emb    = (const float*)d_in[3];
    const float* user_proj_W = (const float*)d_in[4];
    const float* user_proj_b = (const float*)d_in[5];
    const float* item_proj_W = (const float*)d_in[6];
    const float* item_proj_b = (const float*)d_in[7];
    const float* sage_Wl  = (const float*)d_in[8];
    const float* sage_bl  = (const float*)d_in[9];
    const float* sage_Wr  = (const float*)d_in[10];
    const float* bn_gamma = (const float*)d_in[11];
    const float* bn_beta  = (const float*)d_in[12];
    const float* query_W  = (const float*)d_in[13];
    const float* query_b  = (const float*)d_in[14];
    const float* key_W    = (const float*)d_in[15];
    const float* key_b    = (const float*)d_in[16];
    const float* fuse_W   = (const float*)d_in[17];
    const float* fuse_b   = (const float*)d_in[18];
    const float* refine_W = (const float*)d_in[19];
    const float* refine_b = (const float*)d_in[20];
    const int E = in_sizes[1];

    float* S = (float*)d_out;  // f32 [N,D] scratch (agg / Q / fused) and final output

    char* w = (char*)d_ws;
    u16* xb = (u16*)w;          w += (size_t)NNODE * DIM * 2;        // initial features, bf16
    float* h = (float*)w;       w += (size_t)NNODE * DIM * 4;        // hidden, f32
    u16* stackb = (u16*)w;      w += (size_t)NB * NNODE * DIM * 2;   // per-behavior outs, bf16
    float* denom = (float*)w;   w += (size_t)NB * NNODE * 4;         // counts -> 1/denom
    float* logits = (float*)w;  w += (size_t)NNODE * NB * 4;
    int* elist = (int*)w;       w += (size_t)2 * E * 4;
    int* small = (int*)w;       w += 64 * 4;
    float* stats = (float*)w;   w += 256 * 4;

    const size_t HD4 = (size_t)NNODE * DIM * 4;

    // ---- edge preprocessing ----
    hipMemsetAsync(denom, 0, (size_t)NB * NNODE * 4, stream);
    hipMemsetAsync(small, 0, 64 * 4, stream);
    int gE = (E + 255) / 256;
    count_edges<<<gE, 256, 0, stream>>>(edge_index, edge_type, E, (int*)denom, small);
    compute_offs<<<1, 1, 0, stream>>>(small);
    scatter_edges<<<gE, 256, 0, stream>>>(edge_index, edge_type, E, small, elist);
    make_inv_denom<<<(NB * NNODE + 255) / 256, 256, 0, stream>>>((int*)denom, NB * NNODE);

    // ---- initial projection -> xb (bf16) ----
    gemm64<<<2048, 512, 0, stream>>>(user_emb, user_proj_W, user_proj_b,
                                     nullptr, nullptr, xb, NUSER, nullptr, 32);
    gemm64<<<2048, 512, 0, stream>>>(item_feats, item_proj_W, item_proj_b,
                                     nullptr, nullptr, xb + (size_t)NUSER * DIM, NITEM, nullptr, 32);

    // ---- SAGE layers per behavior ----
    for (int b = 0; b < NB; ++b) {
        for (int l = 0; l < NL; ++l) {
            const int bl = b * NL + l;
            hipMemsetAsync(S, 0, HD4, stream);
            hipMemsetAsync(stats, 0, 256 * 4, stream);
            if (l == 0)
                aggregate<<<2048, 256, 0, stream>>>(xb, 1, S, elist, small,
                                                    denom + (size_t)b * NNODE, b);
            else
                aggregate<<<2048, 256, 0, stream>>>(h, 0, S, elist, small,
                                                    denom + (size_t)b * NNODE, b);
            // h = S@Wl + bl + hin@Wr  (dual), stats accumulated
            gemm64<<<2048, 512, 0, stream>>>(S, sage_Wl + (size_t)bl * DIM * DIM,
                                             sage_bl + (size_t)bl * DIM,
                                             (l == 0) ? (const void*)xb : (const void*)h,
                                             sage_Wr + (size_t)bl * DIM * DIM,
                                             h, NNODE, stats,
                                             2 | 4 | ((l == 0) ? 16 : 0));
            if (l < NL - 1)
                bn_apply<<<18750, 256, 0, stream>>>(h, stats,
                                                    bn_gamma + (size_t)bl * DIM,
                                                    bn_beta + (size_t)bl * DIM,
                                                    nullptr, nullptr, 1);
            else
                bn_apply<<<18750, 256, 0, stream>>>(h, stats,
                                                    bn_gamma + (size_t)bl * DIM,
                                                    bn_beta + (size_t)bl * DIM,
                                                    xb, stackb + (size_t)b * NNODE * DIM, 0);
        }
    }

    // ---- attention fusion ----
    gemm64<<<2048, 512, 0, stream>>>(xb, query_W, query_b, nullptr, nullptr,
                                     S, NNODE, nullptr, 8);  // Q -> S
    for (int b = 0; b < NB; ++b) {
        gemm64<<<2048, 512, 0, stream>>>(stackb + (size_t)b * NNODE * DIM,
                                         key_W + (size_t)b * DIM * DIM,
                                         key_b + (size_t)b * DIM,
                                         nullptr, nullptr, h, NNODE, nullptr, 8);  // K_b -> h
        rowdot<<<18750, 256, 0, stream>>>(S, h, logits, b);
    }
    softmax_fuse<<<18750, 256, 0, stream>>>(logits, stackb, h);   // fused -> h
    gemm64<<<2048, 512, 0, stream>>>(h, fuse_W, fuse_b, nullptr, nullptr,
                                     S, NNODE, nullptr, 0);       // fuse -> S
    gemm64<<<2048, 512, 0, stream>>>(S, refine_W, refine_b, nullptr, nullptr,
                                     S, NNODE, nullptr, 1);       // refine in-place -> d_out
}

// Round 3
// 2746.512 us; speedup vs baseline: 4.3525x; 4.3525x over previous
//
#include <hip/hip_runtime.h>
#include <hip/hip_bf16.h>

#define NUSER 100000
#define NITEM 50000
#define NNODE 150000
#define DIM 128
#define NB 3
#define NL 2
#define BN_EPS 1e-5f
#define NT3 (NB * NNODE)        // 450000 per-(behavior,node) counters
#define NT3P 450560             // padded to 440 * 1024
#define SCAN_BLOCKS 440

typedef unsigned short u16;

__device__ __forceinline__ float b2f(u16 u) {
    return __uint_as_float(((unsigned)u) << 16);
}
__device__ __forceinline__ u16 f2b(float f) {
    unsigned x = __float_as_uint(f);
    unsigned r = (x + 0x7fffu + ((x >> 16) & 1u)) >> 16;
    return (u16)r;
}

// ---------------- edge preprocessing: CSR build ----------------

__global__ __launch_bounds__(256) void count_edges(const int* __restrict__ ei,
                                                   const int* __restrict__ et, int E,
                                                   int* __restrict__ cnt) {
    int t = blockIdx.x * 256 + threadIdx.x;
    if (t >= E) return;
    atomicAdd(&cnt[et[t] * NNODE + ei[E + t]], 1);
}

// per-block sums of 1024 counts
__global__ __launch_bounds__(256) void scan1(const int* __restrict__ cnt, int* __restrict__ bsum) {
    __shared__ int sh[256];
    int tid = threadIdx.x;
    int base = blockIdx.x * 1024 + tid * 4;
    int4 v = *(const int4*)(cnt + base);
    sh[tid] = v.x + v.y + v.z + v.w;
    __syncthreads();
    for (int off = 128; off > 0; off >>= 1) {
        if (tid < off) sh[tid] += sh[tid + off];
        __syncthreads();
    }
    if (tid == 0) bsum[blockIdx.x] = sh[0];
}

// exclusive scan of block sums (single block)
__global__ __launch_bounds__(512) void scan2(int* __restrict__ bsum, int nb) {
    __shared__ int sh[512];
    int tid = threadIdx.x;
    sh[tid] = (tid < nb) ? bsum[tid] : 0;
    __syncthreads();
    for (int off = 1; off < 512; off <<= 1) {
        int v = sh[tid];
        int add = (tid >= off) ? sh[tid - off] : 0;
        __syncthreads();
        sh[tid] = v + add;
        __syncthreads();
    }
    if (tid < nb) bsum[tid] = (tid == 0) ? 0 : sh[tid - 1];
}

// final exclusive prefix -> row_start, and cursor copy
__global__ __launch_bounds__(256) void scan3(const int* __restrict__ cnt, const int* __restrict__ bsum,
                                             int* __restrict__ row_start, int* __restrict__ cur) {
    __shared__ int sh[256];
    int tid = threadIdx.x;
    int base = blockIdx.x * 1024 + tid * 4;
    int4 v = *(const int4*)(cnt + base);
    int s = v.x + v.y + v.z + v.w;
    sh[tid] = s;
    __syncthreads();
    for (int off = 1; off < 256; off <<= 1) {
        int a = sh[tid];
        int add = (tid >= off) ? sh[tid - off] : 0;
        __syncthreads();
        sh[tid] = a + add;
        __syncthreads();
    }
    int excl = ((tid == 0) ? 0 : sh[tid - 1]) + bsum[blockIdx.x];
    int4 o;
    o.x = excl; o.y = excl + v.x; o.z = o.y + v.y; o.w = o.z + v.z;
    *(int4*)(row_start + base) = o;
    *(int4*)(cur + base) = o;
}

__global__ __launch_bounds__(256) void scatter_csr(const int* __restrict__ ei,
                                                   const int* __restrict__ et, int E,
                                                   int* __restrict__ cur, int* __restrict__ adj) {
    int t = blockIdx.x * 256 + threadIdx.x;
    if (t >= E) return;
    int pos = atomicAdd(&cur[et[t] * NNODE + ei[E + t]], 1);
    adj[pos] = ei[t];
}

// ---------------- aggregation: CSR gather, agg[n] = mean of h[src] ----------------

__global__ __launch_bounds__(256) void aggregate_csr(const void* __restrict__ hv, int in_bf16,
                                                     float* __restrict__ agg,
                                                     const int* __restrict__ adj,
                                                     const int* __restrict__ row_start,
                                                     const int* __restrict__ cnt, int b) {
    int t = blockIdx.x * 256 + threadIdx.x;
    int n = t >> 5;
    if (n >= NNODE) return;
    int lane = t & 31;
    int base = b * NNODE + n;
    int s0 = row_start[base];
    int deg = cnt[base];
    float ax = 0.f, ay = 0.f, az = 0.f, aw = 0.f;
    for (int e = 0; e < deg; ++e) {
        int src = adj[s0 + e];
        if (in_bf16) {
            ushort4 u = *(const ushort4*)((const u16*)hv + (size_t)src * DIM + lane * 4);
            ax += b2f(u.x); ay += b2f(u.y); az += b2f(u.z); aw += b2f(u.w);
        } else {
            float4 f = *(const float4*)((const float*)hv + (size_t)src * DIM + lane * 4);
            ax += f.x; ay += f.y; az += f.z; aw += f.w;
        }
    }
    float sc = 1.0f / (float)(deg > 1 ? deg : 1);
    float4 o;
    o.x = ax * sc; o.y = ay * sc; o.z = az * sc; o.w = aw * sc;
    *(float4*)(agg + (size_t)n * DIM + lane * 4) = o;
}

// ---------------- tiled GEMM: C = A1@W1 + bias [+ A2@W2], 64x128 tile, LDS-staged ----------------
// flags: 1=relu, 2=dual, 4=stats, 8=A1 bf16, 16=A2 bf16, 32=C bf16
// One tile per block. LDS = As(32KB) + Ws(32KB) = 64KB -> 2 blocks/CU.
// In-place safe for C aliasing A1/A2 (block reads only its own rows, all
// reads complete before its stores).

__global__ __launch_bounds__(256) void gemm_t(const void* A1v, const float* __restrict__ W1,
                                              const float* __restrict__ bias,
                                              const void* A2v, const float* __restrict__ W2,
                                              void* Cv, int M, float* __restrict__ stats,
                                              int flags) {
    __shared__ float As[64 * DIM];
    __shared__ float Ws[64 * DIM];
    const int tid = threadIdx.x;
    const int c4 = (tid & 31) * 4;
    const int rb = tid >> 5;           // 0..7
    const int r0 = blockIdx.x * 64;
    const int npass = (flags & 2) ? 2 : 1;
    float acc[8][4];
#pragma unroll
    for (int i = 0; i < 8; ++i)
#pragma unroll
        for (int j = 0; j < 4; ++j) acc[i][j] = 0.f;

    for (int p = 0; p < npass; ++p) {
        const void* Av = p ? A2v : A1v;
        const float* W = p ? W2 : W1;
        const bool abf = p ? ((flags & 16) != 0) : ((flags & 8) != 0);
        __syncthreads();  // protect As/Ws from previous pass readers
        // stage A tile: 64 rows x 128 (f32 in LDS)
        for (int f = tid; f < 2048; f += 256) {
            int row = f >> 5;
            int col4 = (f & 31) * 4;
            int gr = r0 + row;
            float4 v;
            if (gr < M) {
                if (abf) {
                    ushort4 u = *(const ushort4*)((const u16*)Av + (size_t)gr * DIM + col4);
                    v.x = b2f(u.x); v.y = b2f(u.y); v.z = b2f(u.z); v.w = b2f(u.w);
                } else {
                    v = *(const float4*)((const float*)Av + (size_t)gr * DIM + col4);
                }
            } else {
                v.x = v.y = v.z = v.w = 0.f;
            }
            *(float4*)&As[row * DIM + col4] = v;
        }
        for (int kc = 0; kc < DIM; kc += 64) {
            if (kc) __syncthreads();  // previous chunk compute done before Ws overwrite
            for (int f = tid; f < 2048; f += 256)
                ((float4*)Ws)[f] = *(const float4*)(W + (size_t)kc * DIM + f * 4);
            __syncthreads();
            for (int k4 = 0; k4 < 64; k4 += 4) {
                float4 a[8];
#pragma unroll
                for (int i = 0; i < 8; ++i)
                    a[i] = *(const float4*)&As[(rb + 8 * i) * DIM + kc + k4];
#pragma unroll
                for (int j = 0; j < 4; ++j) {
                    const float4 w = *(const float4*)&Ws[(k4 + j) * DIM + c4];
#pragma unroll
                    for (int i = 0; i < 8; ++i) {
                        float aj = (j == 0) ? a[i].x : (j == 1) ? a[i].y : (j == 2) ? a[i].z : a[i].w;
                        acc[i][0] = fmaf(aj, w.x, acc[i][0]);
                        acc[i][1] = fmaf(aj, w.y, acc[i][1]);
                        acc[i][2] = fmaf(aj, w.z, acc[i][2]);
                        acc[i][3] = fmaf(aj, w.w, acc[i][3]);
                    }
                }
            }
        }
    }

    // epilogue
    const float4 bb = *(const float4*)&bias[c4];
    float rs0 = 0, rs1 = 0, rs2 = 0, rs3 = 0;
    float rq0 = 0, rq1 = 0, rq2 = 0, rq3 = 0;
#pragma unroll
    for (int i = 0; i < 8; ++i) {
        int row = r0 + rb + 8 * i;
        if (row >= M) continue;
        float o0 = acc[i][0] + bb.x, o1 = acc[i][1] + bb.y;
        float o2 = acc[i][2] + bb.z, o3 = acc[i][3] + bb.w;
        if (flags & 1) {
            o0 = fmaxf(o0, 0.f); o1 = fmaxf(o1, 0.f);
            o2 = fmaxf(o2, 0.f); o3 = fmaxf(o3, 0.f);
        }
        if (flags & 4) {
            rs0 += o0; rs1 += o1; rs2 += o2; rs3 += o3;
            rq0 += o0 * o0; rq1 += o1 * o1; rq2 += o2 * o2; rq3 += o3 * o3;
        }
        if (flags & 32) {
            ushort4 u;
            u.x = f2b(o0); u.y = f2b(o1); u.z = f2b(o2); u.w = f2b(o3);
            *(ushort4*)((u16*)Cv + (size_t)row * DIM + c4) = u;
        } else {
            float4 o;
            o.x = o0; o.y = o1; o.z = o2; o.w = o3;
            *(float4*)((float*)Cv + (size_t)row * DIM + c4) = o;
        }
    }
    if (flags & 4) {
        // reuse Ws as ssum[128] + ssq[128]
        float* ssum = Ws;
        float* ssq = Ws + DIM;
        __syncthreads();
        if (tid < 256) Ws[tid] = 0.f;
        __syncthreads();
        atomicAdd(&ssum[c4 + 0], rs0); atomicAdd(&ssum[c4 + 1], rs1);
        atomicAdd(&ssum[c4 + 2], rs2); atomicAdd(&ssum[c4 + 3], rs3);
        atomicAdd(&ssq[c4 + 0], rq0);  atomicAdd(&ssq[c4 + 1], rq1);
        atomicAdd(&ssq[c4 + 2], rq2);  atomicAdd(&ssq[c4 + 3], rq3);
        __syncthreads();
        if (tid < DIM) {
            atomicAdd(&stats[tid], ssum[tid]);
            atomicAdd(&stats[DIM + tid], ssq[tid]);
        }
    }
}

// ---------------- BatchNorm apply ----------------

__global__ __launch_bounds__(256) void bn_apply(float* __restrict__ h, const float* __restrict__ stats,
                                                const float* __restrict__ gamma, const float* __restrict__ beta,
                                                const u16* __restrict__ addx, u16* __restrict__ outb,
                                                int relu) {
    int t = blockIdx.x * 256 + threadIdx.x;
    if (t >= NNODE * 32) return;
    int n = t >> 5;
    int d = (t & 31) * 4;
    const float invN = 1.0f / (float)NNODE;
    float4 s = *(const float4*)&stats[d];
    float4 sq = *(const float4*)&stats[DIM + d];
    float4 g = *(const float4*)&gamma[d];
    float4 be = *(const float4*)&beta[d];
    float mx = s.x * invN, my = s.y * invN, mz = s.z * invN, mw = s.w * invN;
    float cx = g.x * rsqrtf(fmaxf(sq.x * invN - mx * mx, 0.f) + BN_EPS);
    float cy = g.y * rsqrtf(fmaxf(sq.y * invN - my * my, 0.f) + BN_EPS);
    float cz = g.z * rsqrtf(fmaxf(sq.z * invN - mz * mz, 0.f) + BN_EPS);
    float cw = g.w * rsqrtf(fmaxf(sq.w * invN - mw * mw, 0.f) + BN_EPS);
    float4 v = *(float4*)(h + (size_t)n * DIM + d);
    v.x = (v.x - mx) * cx + be.x;
    v.y = (v.y - my) * cy + be.y;
    v.z = (v.z - mz) * cz + be.z;
    v.w = (v.w - mw) * cw + be.w;
    if (relu) {
        v.x = fmaxf(v.x, 0.f); v.y = fmaxf(v.y, 0.f);
        v.z = fmaxf(v.z, 0.f); v.w = fmaxf(v.w, 0.f);
    }
    if (addx) {
        ushort4 u = *(const ushort4*)(addx + (size_t)n * DIM + d);
        v.x += b2f(u.x); v.y += b2f(u.y); v.z += b2f(u.z); v.w += b2f(u.w);
    }
    if (outb) {
        ushort4 o;
        o.x = f2b(v.x); o.y = f2b(v.y); o.z = f2b(v.z); o.w = f2b(v.w);
        *(ushort4*)(outb + (size_t)n * DIM + d) = o;
    } else {
        *(float4*)(h + (size_t)n * DIM + d) = v;
    }
}

// ---------------- attention helpers ----------------

__global__ __launch_bounds__(256) void rowdot(const float* __restrict__ Q, const float* __restrict__ K,
                                              float* __restrict__ logits, int b) {
    int t = blockIdx.x * 256 + threadIdx.x;
    int n = t >> 5;
    int lane = t & 31;
    if (n >= NNODE) return;
    const float4 q = *(const float4*)(Q + (size_t)n * DIM + lane * 4);
    const float4 k = *(const float4*)(K + (size_t)n * DIM + lane * 4);
    float p = q.x * k.x + q.y * k.y + q.z * k.z + q.w * k.w;
    p += __shfl_down(p, 16);
    p += __shfl_down(p, 8);
    p += __shfl_down(p, 4);
    p += __shfl_down(p, 2);
    p += __shfl_down(p, 1);
    if (lane == 0) logits[n * NB + b] = p;
}

__global__ __launch_bounds__(256) void softmax_fuse(const float* __restrict__ logits,
                                                    const u16* __restrict__ stk,
                                                    float* __restrict__ out) {
    int t = blockIdx.x * 256 + threadIdx.x;
    if (t >= NNODE * 32) return;
    int n = t >> 5;
    int d = (t & 31) * 4;
    float l0 = logits[n * NB + 0];
    float l1 = logits[n * NB + 1];
    float l2 = logits[n * NB + 2];
    float m = fmaxf(l0, fmaxf(l1, l2));
    float e0 = expf(l0 - m), e1 = expf(l1 - m), e2 = expf(l2 - m);
    float inv = 1.0f / (e0 + e1 + e2);
    float w0 = e0 * inv, w1 = e1 * inv, w2 = e2 * inv;
    size_t base = (size_t)n * DIM + d;
    ushort4 u0 = *(const ushort4*)(stk + base);
    ushort4 u1 = *(const ushort4*)(stk + (size_t)NNODE * DIM + base);
    ushort4 u2 = *(const ushort4*)(stk + (size_t)2 * NNODE * DIM + base);
    float4 o;
    o.x = w0 * b2f(u0.x) + w1 * b2f(u1.x) + w2 * b2f(u2.x);
    o.y = w0 * b2f(u0.y) + w1 * b2f(u1.y) + w2 * b2f(u2.y);
    o.z = w0 * b2f(u0.z) + w1 * b2f(u1.z) + w2 * b2f(u2.z);
    o.w = w0 * b2f(u0.w) + w1 * b2f(u1.w) + w2 * b2f(u2.w);
    *(float4*)(out + base) = o;
}

// ---------------- launch ----------------

extern "C" void kernel_launch(void* const* d_in, const int* in_sizes, int n_in,
                              void* d_out, int out_size, void* d_ws, size_t ws_size,
                              hipStream_t stream) {
    const int* edge_index    = (const int*)d_in[0];
    const int* edge_type     = (const int*)d_in[1];
    const float* item_feats  = (const float*)d_in[2];
    const float* user_emb    = (const float*)d_in[3];
    const float* user_proj_W = (const float*)d_in[4];
    const float* user_proj_b = (const float*)d_in[5];
    const float* item_proj_W = (const float*)d_in[6];
    const float* item_proj_b = (const float*)d_in[7];
    const float* sage_Wl  = (const float*)d_in[8];
    const float* sage_bl  = (const float*)d_in[9];
    const float* sage_Wr  = (const float*)d_in[10];
    const float* bn_gamma = (const float*)d_in[11];
    const float* bn_beta  = (const float*)d_in[12];
    const float* query_W  = (const float*)d_in[13];
    const float* query_b  = (const float*)d_in[14];
    const float* key_W    = (const float*)d_in[15];
    const float* key_b    = (const float*)d_in[16];
    const float* fuse_W   = (const float*)d_in[17];
    const float* fuse_b   = (const float*)d_in[18];
    const float* refine_W = (const float*)d_in[19];
    const float* refine_b = (const float*)d_in[20];
    const int E = in_sizes[1];

    float* S = (float*)d_out;  // f32 [N,D] scratch (agg / Q / fused) and final output

    char* w = (char*)d_ws;
    u16* xb = (u16*)w;          w += (size_t)NNODE * DIM * 2;        // initial features, bf16
    float* h = (float*)w;       w += (size_t)NNODE * DIM * 4;        // hidden, f32
    u16* stackb = (u16*)w;      w += (size_t)NB * NNODE * DIM * 2;   // per-behavior outs, bf16
    int* cnt = (int*)w;         w += (size_t)NT3P * 4;
    int* row_start = (int*)w;   w += (size_t)NT3P * 4;
    int* cur = (int*)w;         w += (size_t)NT3P * 4;
    int* adj = (int*)w;         w += (size_t)E * 4;
    float* logits = (float*)w;  w += (size_t)NNODE * NB * 4;
    int* bsum = (int*)w;        w += 512 * 4;
    float* stats = (float*)w;   w += 256 * 4;

    // ---- CSR build ----
    hipMemsetAsync(cnt, 0, (size_t)NT3P * 4, stream);
    int gE = (E + 255) / 256;
    count_edges<<<gE, 256, 0, stream>>>(edge_index, edge_type, E, cnt);
    scan1<<<SCAN_BLOCKS, 256, 0, stream>>>(cnt, bsum);
    scan2<<<1, 512, 0, stream>>>(bsum, SCAN_BLOCKS);
    scan3<<<SCAN_BLOCKS, 256, 0, stream>>>(cnt, bsum, row_start, cur);
    scatter_csr<<<gE, 256, 0, stream>>>(edge_index, edge_type, E, cur, adj);

    // ---- initial projection -> xb (bf16) ----
    gemm_t<<<(NUSER + 63) / 64, 256, 0, stream>>>(user_emb, user_proj_W, user_proj_b,
                                                  nullptr, nullptr, xb, NUSER, nullptr, 32);
    gemm_t<<<(NITEM + 63) / 64, 256, 0, stream>>>(item_feats, item_proj_W, item_proj_b,
                                                  nullptr, nullptr, xb + (size_t)NUSER * DIM,
                                                  NITEM, nullptr, 32);

    const int TILES = (NNODE + 63) / 64;

    // ---- SAGE layers per behavior ----
    for (int b = 0; b < NB; ++b) {
        for (int l = 0; l < NL; ++l) {
            const int bl = b * NL + l;
            hipMemsetAsync(stats, 0, 256 * 4, stream);
            if (l == 0)
                aggregate_csr<<<18750, 256, 0, stream>>>(xb, 1, S, adj, row_start, cnt, b);
            else
                aggregate_csr<<<18750, 256, 0, stream>>>(h, 0, S, adj, row_start, cnt, b);
            // h = S@Wl + bl + hin@Wr  (dual), stats accumulated
            gemm_t<<<TILES, 256, 0, stream>>>(S, sage_Wl + (size_t)bl * DIM * DIM,
                                              sage_bl + (size_t)bl * DIM,
                                              (l == 0) ? (const void*)xb : (const void*)h,
                                              sage_Wr + (size_t)bl * DIM * DIM,
                                              h, NNODE, stats,
                                              2 | 4 | ((l == 0) ? 16 : 0));
            if (l < NL - 1)
                bn_apply<<<18750, 256, 0, stream>>>(h, stats,
                                                    bn_gamma + (size_t)bl * DIM,
                                                    bn_beta + (size_t)bl * DIM,
                                                    nullptr, nullptr, 1);
            else
                bn_apply<<<18750, 256, 0, stream>>>(h, stats,
                                                    bn_gamma + (size_t)bl * DIM,
                                                    bn_beta + (size_t)bl * DIM,
                                                    xb, stackb + (size_t)b * NNODE * DIM, 0);
        }
    }

    // ---- attention fusion ----
    gemm_t<<<TILES, 256, 0, stream>>>(xb, query_W, query_b, nullptr, nullptr,
                                      S, NNODE, nullptr, 8);  // Q -> S
    for (int b = 0; b < NB; ++b) {
        gemm_t<<<TILES, 256, 0, stream>>>(stackb + (size_t)b * NNODE * DIM,
                                          key_W + (size_t)b * DIM * DIM,
                                          key_b + (size_t)b * DIM,
                                          nullptr, nullptr, h, NNODE, nullptr, 8);  // K_b -> h
        rowdot<<<18750, 256, 0, stream>>>(S, h, logits, b);
    }
    softmax_fuse<<<18750, 256, 0, stream>>>(logits, stackb, h);   // fused -> h
    gemm_t<<<TILES, 256, 0, stream>>>(h, fuse_W, fuse_b, nullptr, nullptr,
                                      S, NNODE, nullptr, 0);      // fuse -> S
    gemm_t<<<TILES, 256, 0, stream>>>(S, refine_W, refine_b, nullptr, nullptr,
                                      S, NNODE, nullptr, 1);      // refine in-place -> d_out
}

// Round 4
// 1870.181 us; speedup vs baseline: 6.3920x; 1.4686x over previous
//
#include <hip/hip_runtime.h>
#include <hip/hip_bf16.h>

#define NUSER 100000
#define NITEM 50000
#define NNODE 150000
#define DIM 128
#define NB 3
#define NL 2
#define BN_EPS 1e-5f
#define NT3P 450560             // 440 * 1024, padded NB*NNODE
#define SCAN_BLOCKS 440

typedef unsigned short u16;
typedef __attribute__((ext_vector_type(8))) short bf16x8;
typedef __attribute__((ext_vector_type(4))) float f32x4;

__device__ __forceinline__ float b2f(u16 u) {
    return __uint_as_float(((unsigned)u) << 16);
}
__device__ __forceinline__ u16 f2b(float f) {
    unsigned x = __float_as_uint(f);
    unsigned r = (x + 0x7fffu + ((x >> 16) & 1u)) >> 16;
    return (u16)r;
}

// ---------------- CSR build ----------------

__global__ __launch_bounds__(256) void count_edges(const int* __restrict__ ei,
                                                   const int* __restrict__ et, int E,
                                                   int* __restrict__ cnt) {
    int t = blockIdx.x * 256 + threadIdx.x;
    if (t >= E) return;
    atomicAdd(&cnt[et[t] * NNODE + ei[E + t]], 1);
}

__global__ __launch_bounds__(256) void scan1(const int* __restrict__ cnt, int* __restrict__ bsum) {
    __shared__ int sh[256];
    int tid = threadIdx.x;
    int base = blockIdx.x * 1024 + tid * 4;
    int4 v = *(const int4*)(cnt + base);
    sh[tid] = v.x + v.y + v.z + v.w;
    __syncthreads();
    for (int off = 128; off > 0; off >>= 1) {
        if (tid < off) sh[tid] += sh[tid + off];
        __syncthreads();
    }
    if (tid == 0) bsum[blockIdx.x] = sh[0];
}

__global__ __launch_bounds__(512) void scan2(int* __restrict__ bsum, int nb) {
    __shared__ int sh[512];
    int tid = threadIdx.x;
    sh[tid] = (tid < nb) ? bsum[tid] : 0;
    __syncthreads();
    for (int off = 1; off < 512; off <<= 1) {
        int v = sh[tid];
        int add = (tid >= off) ? sh[tid - off] : 0;
        __syncthreads();
        sh[tid] = v + add;
        __syncthreads();
    }
    if (tid < nb) bsum[tid] = (tid == 0) ? 0 : sh[tid - 1];
}

__global__ __launch_bounds__(256) void scan3(const int* __restrict__ cnt, const int* __restrict__ bsum,
                                             int* __restrict__ row_start, int* __restrict__ cur) {
    __shared__ int sh[256];
    int tid = threadIdx.x;
    int base = blockIdx.x * 1024 + tid * 4;
    int4 v = *(const int4*)(cnt + base);
    sh[tid] = v.x + v.y + v.z + v.w;
    __syncthreads();
    for (int off = 1; off < 256; off <<= 1) {
        int a = sh[tid];
        int add = (tid >= off) ? sh[tid - off] : 0;
        __syncthreads();
        sh[tid] = a + add;
        __syncthreads();
    }
    int excl = ((tid == 0) ? 0 : sh[tid - 1]) + bsum[blockIdx.x];
    int4 o;
    o.x = excl; o.y = excl + v.x; o.z = o.y + v.y; o.w = o.z + v.z;
    *(int4*)(row_start + base) = o;
    *(int4*)(cur + base) = o;
}

__global__ __launch_bounds__(256) void scatter_csr(const int* __restrict__ ei,
                                                   const int* __restrict__ et, int E,
                                                   int* __restrict__ cur, int* __restrict__ adj) {
    int t = blockIdx.x * 256 + threadIdx.x;
    if (t >= E) return;
    int pos = atomicAdd(&cur[et[t] * NNODE + ei[E + t]], 1);
    adj[pos] = ei[t];
}

// ---------------- dtype converters ----------------

__global__ __launch_bounds__(256) void xconv(const float* __restrict__ src, u16* __restrict__ dst, int n4) {
    int t = blockIdx.x * 256 + threadIdx.x;
    if (t >= n4) return;
    float4 v = ((const float4*)src)[t];
    ushort4 o;
    o.x = f2b(v.x); o.y = f2b(v.y); o.z = f2b(v.z); o.w = f2b(v.w);
    ((ushort4*)dst)[t] = o;
}

// transpose + bf16: dst[m][n][k] = src[m][k][n], 128x128 each
__global__ __launch_bounds__(256) void wconv(const float* __restrict__ src, u16* __restrict__ dst, int nmat) {
    int t = blockIdx.x * 256 + threadIdx.x;
    if (t >= nmat * 16384) return;
    int m = t >> 14, idx = t & 16383;
    int k = idx >> 7, n = idx & 127;
    dst[(m << 14) + (n << 7) + k] = f2b(src[t]);
}

// ---------------- aggregation: CSR gather, bf16 in -> bf16 out ----------------

__global__ __launch_bounds__(256) void aggregate_b(const u16* __restrict__ hv,
                                                   u16* __restrict__ aggb,
                                                   const int* __restrict__ adj,
                                                   const int* __restrict__ row_start,
                                                   const int* __restrict__ cnt, int b) {
    int t = blockIdx.x * 256 + threadIdx.x;
    int n = t >> 5;
    if (n >= NNODE) return;
    int lane = t & 31;
    int base = b * NNODE + n;
    int s0 = row_start[base];
    int deg = cnt[base];
    float ax = 0.f, ay = 0.f, az = 0.f, aw = 0.f;
    for (int e = 0; e < deg; ++e) {
        int src = adj[s0 + e];
        ushort4 u = *(const ushort4*)(hv + (size_t)src * DIM + lane * 4);
        ax += b2f(u.x); ay += b2f(u.y); az += b2f(u.z); aw += b2f(u.w);
    }
    float sc = 1.0f / (float)(deg > 1 ? deg : 1);
    ushort4 o;
    o.x = f2b(ax * sc); o.y = f2b(ay * sc); o.z = f2b(az * sc); o.w = f2b(aw * sc);
    *(ushort4*)(aggb + (size_t)n * DIM + lane * 4) = o;
}

// ---------------- MFMA GEMM: C = A1@W1^T' + bias [+ A2@W2], 64x128 tile ----------------
// Weights pre-transposed bf16: Wt[n][k]. flags: 1=relu, 2=dual, 4=stats,
// 32=C bf16, 64=logits mode (no C store; logits[row*NB+bidx] += (C+bias)·Q[row]).
// In-place safe (sync before stores; block owns its 64 rows).

__global__ __launch_bounds__(256) void gemm_mfma(
    const u16* __restrict__ A1, const u16* __restrict__ Wt1,
    const float* __restrict__ bias,
    const u16* __restrict__ A2, const u16* __restrict__ Wt2,
    void* __restrict__ Cv, int M, float* __restrict__ stats,
    const float* __restrict__ Qf, float* __restrict__ logits, int bidx,
    int flags) {
    __shared__ float sstat[256];
    const int tid = threadIdx.x;
    const int wave = tid >> 6;
    const int lane = tid & 63;
    const int q = lane >> 4;
    const int rlo = lane & 15;
    const int r0 = blockIdx.x * 64;
    if (flags & 4) sstat[tid] = 0.f;

    f32x4 acc[4][2];
#pragma unroll
    for (int t = 0; t < 4; ++t)
#pragma unroll
        for (int c = 0; c < 2; ++c) acc[t][c] = (f32x4)0.f;

    const bf16x8 zf = (bf16x8)(short)0;
    const int npass = (flags & 2) ? 2 : 1;
    for (int p = 0; p < npass; ++p) {
        const u16* A = p ? A2 : A1;
        const u16* Wt = p ? Wt2 : Wt1;
#pragma unroll
        for (int kc = 0; kc < DIM; kc += 32) {
            bf16x8 a[4], bf[2];
#pragma unroll
            for (int t = 0; t < 4; ++t) {
                int row = r0 + 16 * t + rlo;
                a[t] = (row < M) ? *(const bf16x8*)(A + (size_t)row * DIM + kc + q * 8) : zf;
            }
#pragma unroll
            for (int c = 0; c < 2; ++c) {
                int col = wave * 32 + 16 * c + rlo;
                bf[c] = *(const bf16x8*)(Wt + (size_t)col * DIM + kc + q * 8);
            }
#pragma unroll
            for (int t = 0; t < 4; ++t)
#pragma unroll
                for (int c = 0; c < 2; ++c)
                    acc[t][c] = __builtin_amdgcn_mfma_f32_16x16x32_bf16(a[t], bf[c], acc[t][c], 0, 0, 0);
        }
    }
    __syncthreads();  // all global reads drained before stores (in-place safety)

    const int col0 = wave * 32 + rlo;
    const int col1 = col0 + 16;
    const float b0 = bias[col0];
    const float b1 = bias[col1];

    if (flags & 64) {
#pragma unroll
        for (int t = 0; t < 4; ++t) {
#pragma unroll
            for (int reg = 0; reg < 4; ++reg) {
                int row = r0 + 16 * t + q * 4 + reg;
                if (row < M) {
                    float v = (acc[t][0][reg] + b0) * Qf[(size_t)row * DIM + col0]
                            + (acc[t][1][reg] + b1) * Qf[(size_t)row * DIM + col1];
                    v += __shfl_xor(v, 1);
                    v += __shfl_xor(v, 2);
                    v += __shfl_xor(v, 4);
                    v += __shfl_xor(v, 8);
                    if (rlo == 0) atomicAdd(&logits[row * NB + bidx], v);
                }
            }
        }
        return;
    }

    float rs0 = 0, rq0 = 0, rs1 = 0, rq1 = 0;
#pragma unroll
    for (int t = 0; t < 4; ++t) {
#pragma unroll
        for (int reg = 0; reg < 4; ++reg) {
            int row = r0 + 16 * t + q * 4 + reg;
            if (row >= M) continue;
            float v0 = acc[t][0][reg] + b0;
            float v1 = acc[t][1][reg] + b1;
            if (flags & 1) { v0 = fmaxf(v0, 0.f); v1 = fmaxf(v1, 0.f); }
            if (flags & 4) { rs0 += v0; rq0 += v0 * v0; rs1 += v1; rq1 += v1 * v1; }
            if (flags & 32) {
                ((u16*)Cv)[(size_t)row * DIM + col0] = f2b(v0);
                ((u16*)Cv)[(size_t)row * DIM + col1] = f2b(v1);
            } else {
                ((float*)Cv)[(size_t)row * DIM + col0] = v0;
                ((float*)Cv)[(size_t)row * DIM + col1] = v1;
            }
        }
    }
    if (flags & 4) {
        atomicAdd(&sstat[col0], rs0);
        atomicAdd(&sstat[DIM + col0], rq0);
        atomicAdd(&sstat[col1], rs1);
        atomicAdd(&sstat[DIM + col1], rq1);
        __syncthreads();
        if (tid < DIM) {
            atomicAdd(&stats[tid], sstat[tid]);
            atomicAdd(&stats[DIM + tid], sstat[DIM + tid]);
        }
    }
}

// ---------------- BatchNorm apply: f32 in -> bf16 out (+opt relu / residual) ----------------

__global__ __launch_bounds__(256) void bn_apply(const float* __restrict__ h, const float* __restrict__ stats,
                                                const float* __restrict__ gamma, const float* __restrict__ beta,
                                                const u16* __restrict__ addx, u16* __restrict__ outb,
                                                int relu) {
    int t = blockIdx.x * 256 + threadIdx.x;
    if (t >= NNODE * 32) return;
    int n = t >> 5;
    int d = (t & 31) * 4;
    const float invN = 1.0f / (float)NNODE;
    float4 s = *(const float4*)&stats[d];
    float4 sq = *(const float4*)&stats[DIM + d];
    float4 g = *(const float4*)&gamma[d];
    float4 be = *(const float4*)&beta[d];
    float mx = s.x * invN, my = s.y * invN, mz = s.z * invN, mw = s.w * invN;
    float cx = g.x * rsqrtf(fmaxf(sq.x * invN - mx * mx, 0.f) + BN_EPS);
    float cy = g.y * rsqrtf(fmaxf(sq.y * invN - my * my, 0.f) + BN_EPS);
    float cz = g.z * rsqrtf(fmaxf(sq.z * invN - mz * mz, 0.f) + BN_EPS);
    float cw = g.w * rsqrtf(fmaxf(sq.w * invN - mw * mw, 0.f) + BN_EPS);
    float4 v = *(const float4*)(h + (size_t)n * DIM + d);
    v.x = (v.x - mx) * cx + be.x;
    v.y = (v.y - my) * cy + be.y;
    v.z = (v.z - mz) * cz + be.z;
    v.w = (v.w - mw) * cw + be.w;
    if (relu) {
        v.x = fmaxf(v.x, 0.f); v.y = fmaxf(v.y, 0.f);
        v.z = fmaxf(v.z, 0.f); v.w = fmaxf(v.w, 0.f);
    }
    if (addx) {
        ushort4 u = *(const ushort4*)(addx + (size_t)n * DIM + d);
        v.x += b2f(u.x); v.y += b2f(u.y); v.z += b2f(u.z); v.w += b2f(u.w);
    }
    ushort4 o;
    o.x = f2b(v.x); o.y = f2b(v.y); o.z = f2b(v.z); o.w = f2b(v.w);
    *(ushort4*)(outb + (size_t)n * DIM + d) = o;
}

// ---------------- softmax over behaviours + weighted sum -> bf16 ----------------

__global__ __launch_bounds__(256) void softmax_fuse(const float* __restrict__ logits,
                                                    const u16* __restrict__ stk,
                                                    u16* __restrict__ outb) {
    int t = blockIdx.x * 256 + threadIdx.x;
    if (t >= NNODE * 32) return;
    int n = t >> 5;
    int d = (t & 31) * 4;
    float l0 = logits[n * NB + 0];
    float l1 = logits[n * NB + 1];
    float l2 = logits[n * NB + 2];
    float m = fmaxf(l0, fmaxf(l1, l2));
    float e0 = expf(l0 - m), e1 = expf(l1 - m), e2 = expf(l2 - m);
    float inv = 1.0f / (e0 + e1 + e2);
    float w0 = e0 * inv, w1 = e1 * inv, w2 = e2 * inv;
    size_t base = (size_t)n * DIM + d;
    ushort4 u0 = *(const ushort4*)(stk + base);
    ushort4 u1 = *(const ushort4*)(stk + (size_t)NNODE * DIM + base);
    ushort4 u2 = *(const ushort4*)(stk + (size_t)2 * NNODE * DIM + base);
    ushort4 o;
    o.x = f2b(w0 * b2f(u0.x) + w1 * b2f(u1.x) + w2 * b2f(u2.x));
    o.y = f2b(w0 * b2f(u0.y) + w1 * b2f(u1.y) + w2 * b2f(u2.y));
    o.z = f2b(w0 * b2f(u0.z) + w1 * b2f(u1.z) + w2 * b2f(u2.z));
    o.w = f2b(w0 * b2f(u0.w) + w1 * b2f(u1.w) + w2 * b2f(u2.w));
    *(ushort4*)(outb + base) = o;
}

// ---------------- launch ----------------

extern "C" void kernel_launch(void* const* d_in, const int* in_sizes, int n_in,
                              void* d_out, int out_size, void* d_ws, size_t ws_size,
                              hipStream_t stream) {
    const int* edge_index    = (const int*)d_in[0];
    const int* edge_type     = (const int*)d_in[1];
    const float* item_feats  = (const float*)d_in[2];
    const float* user_emb    = (const float*)d_in[3];
    const float* user_proj_W = (const float*)d_in[4];
    const float* user_proj_b = (const float*)d_in[5];
    const float* item_proj_W = (const float*)d_in[6];
    const float* item_proj_b = (const float*)d_in[7];
    const float* sage_Wl  = (const float*)d_in[8];
    const float* sage_bl  = (const float*)d_in[9];
    const float* sage_Wr  = (const float*)d_in[10];
    const float* bn_gamma = (const float*)d_in[11];
    const float* bn_beta  = (const float*)d_in[12];
    const float* query_b  = (const float*)d_in[14];
    const float* key_b    = (const float*)d_in[16];
    const float* fuse_b   = (const float*)d_in[18];
    const float* refine_b = (const float*)d_in[20];
    const int E = in_sizes[1];

    float* h32 = (float*)d_out;  // f32 [N,D]: pre-BN h, later Q, finally output

    char* w = (char*)d_ws;
    u16* xb = (u16*)w;          w += (size_t)NNODE * DIM * 2;        // x, bf16
    u16* hb = (u16*)w;          w += (size_t)NNODE * DIM * 2;        // post-BN hidden / staging, bf16
    u16* Sb = (u16*)w;          w += (size_t)NNODE * DIM * 2;        // agg out / fused, bf16
    u16* stackb = (u16*)w;      w += (size_t)NB * NNODE * DIM * 2;   // per-behavior outs, bf16
    int* cnt = (int*)w;         w += (size_t)NT3P * 4;
    int* row_start = (int*)w;   w += (size_t)NT3P * 4;
    int* cur = (int*)w;         w += (size_t)NT3P * 4;
    int* adj = (int*)w;         w += (size_t)E * 4;
    float* logits = (float*)w;  w += (size_t)NNODE * NB * 4;
    u16* wt = (u16*)w;          w += (size_t)20 * 16384 * 2;         // transposed bf16 weights
    int* bsum = (int*)w;        w += 2048;
    float* stats = (float*)w;   w += 1024;

    const u16* wt_user = wt;
    const u16* wt_item = wt + 16384;
    const u16* wt_Wl   = wt + 2 * 16384;   // 6 mats
    const u16* wt_Wr   = wt + 8 * 16384;   // 6 mats
    const u16* wt_q    = wt + 14 * 16384;
    const u16* wt_key  = wt + 15 * 16384;  // 3 mats
    const u16* wt_fuse = wt + 18 * 16384;
    const u16* wt_ref  = wt + 19 * 16384;

    // ---- CSR build ----
    hipMemsetAsync(cnt, 0, (size_t)NT3P * 4, stream);
    int gE = (E + 255) / 256;
    count_edges<<<gE, 256, 0, stream>>>(edge_index, edge_type, E, cnt);
    scan1<<<SCAN_BLOCKS, 256, 0, stream>>>(cnt, bsum);
    scan2<<<1, 512, 0, stream>>>(bsum, SCAN_BLOCKS);
    scan3<<<SCAN_BLOCKS, 256, 0, stream>>>(cnt, bsum, row_start, cur);
    scatter_csr<<<gE, 256, 0, stream>>>(edge_index, edge_type, E, cur, adj);

    // ---- weight + input conversion ----
    wconv<<<64, 256, 0, stream>>>(user_proj_W, (u16*)wt_user, 1);
    wconv<<<64, 256, 0, stream>>>(item_proj_W, (u16*)wt_item, 1);
    wconv<<<384, 256, 0, stream>>>(sage_Wl, (u16*)wt_Wl, 6);
    wconv<<<384, 256, 0, stream>>>(sage_Wr, (u16*)wt_Wr, 6);
    wconv<<<64, 256, 0, stream>>>((const float*)d_in[13], (u16*)wt_q, 1);
    wconv<<<192, 256, 0, stream>>>((const float*)d_in[15], (u16*)wt_key, 3);
    wconv<<<64, 256, 0, stream>>>((const float*)d_in[17], (u16*)wt_fuse, 1);
    wconv<<<64, 256, 0, stream>>>((const float*)d_in[19], (u16*)wt_ref, 1);
    xconv<<<(NUSER * 32 + 255) / 256, 256, 0, stream>>>(user_emb, hb, NUSER * 32);
    xconv<<<(NITEM * 32 + 255) / 256, 256, 0, stream>>>(item_feats, hb + (size_t)NUSER * DIM, NITEM * 32);

    const int TILES = (NNODE + 63) / 64;
    const int TU = (NUSER + 63) / 64;
    const int TI = (NITEM + 63) / 64;

    // ---- initial projection -> xb (bf16) ----
    gemm_mfma<<<TU, 256, 0, stream>>>(hb, wt_user, user_proj_b, nullptr, nullptr,
                                      xb, NUSER, nullptr, nullptr, nullptr, 0, 32);
    gemm_mfma<<<TI, 256, 0, stream>>>(hb + (size_t)NUSER * DIM, wt_item, item_proj_b,
                                      nullptr, nullptr, xb + (size_t)NUSER * DIM,
                                      NITEM, nullptr, nullptr, nullptr, 0, 32);

    // ---- SAGE layers per behavior ----
    for (int b = 0; b < NB; ++b) {
        for (int l = 0; l < NL; ++l) {
            const int bl = b * NL + l;
            hipMemsetAsync(stats, 0, 1024, stream);
            aggregate_b<<<18750, 256, 0, stream>>>((l == 0) ? xb : hb, Sb,
                                                   adj, row_start, cnt, b);
            // h32 = Sb@Wl + bl + hin@Wr (dual, stats)
            gemm_mfma<<<TILES, 256, 0, stream>>>(Sb, wt_Wl + (size_t)bl * 16384,
                                                 sage_bl + (size_t)bl * DIM,
                                                 (l == 0) ? xb : hb,
                                                 wt_Wr + (size_t)bl * 16384,
                                                 h32, NNODE, stats, nullptr, nullptr, 0,
                                                 2 | 4);
            if (l < NL - 1)
                bn_apply<<<18750, 256, 0, stream>>>(h32, stats,
                                                    bn_gamma + (size_t)bl * DIM,
                                                    bn_beta + (size_t)bl * DIM,
                                                    nullptr, hb, 1);
            else
                bn_apply<<<18750, 256, 0, stream>>>(h32, stats,
                                                    bn_gamma + (size_t)bl * DIM,
                                                    bn_beta + (size_t)bl * DIM,
                                                    xb, stackb + (size_t)b * NNODE * DIM, 0);
        }
    }

    // ---- attention fusion ----
    gemm_mfma<<<TILES, 256, 0, stream>>>(xb, wt_q, query_b, nullptr, nullptr,
                                         h32, NNODE, nullptr, nullptr, nullptr, 0, 0);  // Q -> h32
    hipMemsetAsync(logits, 0, (size_t)NNODE * NB * 4, stream);
    for (int b = 0; b < NB; ++b)
        gemm_mfma<<<TILES, 256, 0, stream>>>(stackb + (size_t)b * NNODE * DIM,
                                             wt_key + (size_t)b * 16384,
                                             key_b + (size_t)b * DIM,
                                             nullptr, nullptr, nullptr, NNODE, nullptr,
                                             h32, logits, b, 64);  // logits += K_b . Q
    softmax_fuse<<<18750, 256, 0, stream>>>(logits, stackb, Sb);   // fused -> Sb (bf16)
    gemm_mfma<<<TILES, 256, 0, stream>>>(Sb, wt_fuse, fuse_b, nullptr, nullptr,
                                         hb, NNODE, nullptr, nullptr, nullptr, 0, 32);  // fuse -> hb
    gemm_mfma<<<TILES, 256, 0, stream>>>(hb, wt_ref, refine_b, nullptr, nullptr,
                                         h32, NNODE, nullptr, nullptr, nullptr, 0, 1);  // relu -> d_out
}

// Round 5
// 1771.496 us; speedup vs baseline: 6.7481x; 1.0557x over previous
//
#include <hip/hip_runtime.h>

#define NUSER 100000
#define NITEM 50000
#define NNODE 150000
#define DIM 128
#define NB 3
#define NL 2
#define BN_EPS 1e-5f
#define NT3P 450560             // 440 * 1024, padded NB*NNODE
#define SCAN_BLOCKS 440
#define TILESN 2344             // ceil(NNODE/64)

typedef unsigned short u16;
typedef _Float16 f16;
typedef __attribute__((ext_vector_type(8))) _Float16 f16x8;
typedef __attribute__((ext_vector_type(4))) float f32x4;

__device__ __forceinline__ float h2f(u16 u) { f16 h; __builtin_memcpy(&h, &u, 2); return (float)h; }
__device__ __forceinline__ u16 f2h(float f) { f16 h = (f16)f; u16 u; __builtin_memcpy(&u, &h, 2); return u; }

// ---------------- CSR build ----------------

__global__ __launch_bounds__(256) void count_edges(const int* __restrict__ ei,
                                                   const int* __restrict__ et, int E,
                                                   int* __restrict__ cnt) {
    int t = blockIdx.x * 256 + threadIdx.x;
    if (t >= E) return;
    atomicAdd(&cnt[et[t] * NNODE + ei[E + t]], 1);
}

__global__ __launch_bounds__(256) void scan1(const int* __restrict__ cnt, int* __restrict__ bsum) {
    __shared__ int sh[256];
    int tid = threadIdx.x;
    int base = blockIdx.x * 1024 + tid * 4;
    int4 v = *(const int4*)(cnt + base);
    sh[tid] = v.x + v.y + v.z + v.w;
    __syncthreads();
    for (int off = 128; off > 0; off >>= 1) {
        if (tid < off) sh[tid] += sh[tid + off];
        __syncthreads();
    }
    if (tid == 0) bsum[blockIdx.x] = sh[0];
}

__global__ __launch_bounds__(512) void scan2(int* __restrict__ bsum, int nb) {
    __shared__ int sh[512];
    int tid = threadIdx.x;
    sh[tid] = (tid < nb) ? bsum[tid] : 0;
    __syncthreads();
    for (int off = 1; off < 512; off <<= 1) {
        int v = sh[tid];
        int add = (tid >= off) ? sh[tid - off] : 0;
        __syncthreads();
        sh[tid] = v + add;
        __syncthreads();
    }
    if (tid < nb) bsum[tid] = (tid == 0) ? 0 : sh[tid - 1];
}

__global__ __launch_bounds__(256) void scan3(const int* __restrict__ cnt, const int* __restrict__ bsum,
                                             int* __restrict__ row_start, int* __restrict__ cur) {
    __shared__ int sh[256];
    int tid = threadIdx.x;
    int base = blockIdx.x * 1024 + tid * 4;
    int4 v = *(const int4*)(cnt + base);
    sh[tid] = v.x + v.y + v.z + v.w;
    __syncthreads();
    for (int off = 1; off < 256; off <<= 1) {
        int a = sh[tid];
        int add = (tid >= off) ? sh[tid - off] : 0;
        __syncthreads();
        sh[tid] = a + add;
        __syncthreads();
    }
    int excl = ((tid == 0) ? 0 : sh[tid - 1]) + bsum[blockIdx.x];
    int4 o;
    o.x = excl; o.y = excl + v.x; o.z = o.y + v.y; o.w = o.z + v.z;
    *(int4*)(row_start + base) = o;
    *(int4*)(cur + base) = o;
}

__global__ __launch_bounds__(256) void scatter_csr(const int* __restrict__ ei,
                                                   const int* __restrict__ et, int E,
                                                   int* __restrict__ cur, int* __restrict__ adj) {
    int t = blockIdx.x * 256 + threadIdx.x;
    if (t >= E) return;
    int pos = atomicAdd(&cur[et[t] * NNODE + ei[E + t]], 1);
    adj[pos] = ei[t];
}

// ---------------- weight conversion: all 20 mats, transpose + fp16 ----------------
// dst mat order: 0 user, 1 item, 2..7 Wl, 8..13 Wr, 14 q, 15..17 key, 18 fuse, 19 ref
struct WPtrs { const float* s[8]; };

__global__ __launch_bounds__(256) void wconv_all(WPtrs w, u16* __restrict__ dst) {
    int gid = blockIdx.x * 256 + threadIdx.x;
    if (gid >= 20 * 16384) return;
    int m = gid >> 14, idx = gid & 16383;
    int k = idx & 127, n = idx >> 7;           // dst[m][n][k] contiguous in gid
    const float* src; int li;
    if (m == 0)       { src = w.s[0]; li = 0; }
    else if (m == 1)  { src = w.s[1]; li = 0; }
    else if (m < 8)   { src = w.s[2]; li = m - 2; }
    else if (m < 14)  { src = w.s[3]; li = m - 8; }
    else if (m == 14) { src = w.s[4]; li = 0; }
    else if (m < 18)  { src = w.s[5]; li = m - 15; }
    else if (m == 18) { src = w.s[6]; li = 0; }
    else              { src = w.s[7]; li = 0; }
    dst[(size_t)m * 16384 + idx] = f2h(src[(size_t)li * 16384 + k * 128 + n]);
}

// ---------------- fused prologue + MFMA GEMM (64x128 tile, fp16) ----------------
// mode 1: A1 tile = per-behavior mean-gather of hin rows (CSR)
// mode 2: A1 tile = softmax(logits)-weighted sum of the 3 stack slices (hin = stack base)
// dual if Wt2 != null (A2 = hin rows of this block's own nodes); stats if stats != null.
// C stored fp16. M is always NNODE.

__global__ __launch_bounds__(256) void gemm_fused(
    const u16* __restrict__ hin, const u16* __restrict__ Wt1,
    const float* __restrict__ bias, const u16* __restrict__ Wt2,
    u16* __restrict__ C, float* __restrict__ stats,
    const int* __restrict__ adj, const int* __restrict__ row_start,
    const int* __restrict__ cnt, int b,
    const float* __restrict__ logits, int mode) {
    __shared__ u16 Sh[64][136];   // +8 fp16 pad -> 2-way-max bank aliasing (free)
    __shared__ float sstat[256];
    const int tid = threadIdx.x;
    const int r0 = blockIdx.x * 64;
    if (stats) sstat[tid] = 0.f;

    {   // phase 1: build A1 tile in LDS
        int hw = tid >> 5, ln = tid & 31;
        for (int i = hw; i < 64; i += 8) {
            int n = r0 + i;
            float a0 = 0, a1 = 0, a2 = 0, a3 = 0;
            if (n < NNODE) {
                if (mode == 1) {
                    int base = b * NNODE + n;
                    int s0 = row_start[base], deg = cnt[base];
                    for (int e = 0; e < deg; ++e) {
                        int src = adj[s0 + e];
                        ushort4 u = *(const ushort4*)(hin + (size_t)src * DIM + ln * 4);
                        a0 += h2f(u.x); a1 += h2f(u.y); a2 += h2f(u.z); a3 += h2f(u.w);
                    }
                    float sc = 1.0f / (float)(deg > 1 ? deg : 1);
                    a0 *= sc; a1 *= sc; a2 *= sc; a3 *= sc;
                } else {
                    float l0 = logits[n * NB + 0];
                    float l1 = logits[n * NB + 1];
                    float l2 = logits[n * NB + 2];
                    float mm = fmaxf(l0, fmaxf(l1, l2));
                    float e0 = expf(l0 - mm), e1 = expf(l1 - mm), e2 = expf(l2 - mm);
                    float inv = 1.0f / (e0 + e1 + e2);
                    float w0 = e0 * inv, w1 = e1 * inv, w2 = e2 * inv;
                    size_t off = (size_t)n * DIM + ln * 4;
                    ushort4 u0 = *(const ushort4*)(hin + off);
                    ushort4 u1 = *(const ushort4*)(hin + (size_t)NNODE * DIM + off);
                    ushort4 u2 = *(const ushort4*)(hin + (size_t)2 * NNODE * DIM + off);
                    a0 = w0 * h2f(u0.x) + w1 * h2f(u1.x) + w2 * h2f(u2.x);
                    a1 = w0 * h2f(u0.y) + w1 * h2f(u1.y) + w2 * h2f(u2.y);
                    a2 = w0 * h2f(u0.z) + w1 * h2f(u1.z) + w2 * h2f(u2.z);
                    a3 = w0 * h2f(u0.w) + w1 * h2f(u1.w) + w2 * h2f(u2.w);
                }
            }
            ushort4 o;
            o.x = f2h(a0); o.y = f2h(a1); o.z = f2h(a2); o.w = f2h(a3);
            *(ushort4*)&Sh[i][ln * 4] = o;
        }
    }
    __syncthreads();

    const int wave = tid >> 6, lane = tid & 63, q = lane >> 4, rlo = lane & 15;
    f32x4 acc[4][2];
#pragma unroll
    for (int t = 0; t < 4; ++t) { acc[t][0] = (f32x4)0.f; acc[t][1] = (f32x4)0.f; }
    const bool dual = (Wt2 != nullptr);
    const f16x8 zf = (f16x8)(f16)0.f;
#pragma unroll
    for (int kc = 0; kc < DIM; kc += 32) {
        f16x8 a1v[4], b1v[2];
#pragma unroll
        for (int t = 0; t < 4; ++t)
            a1v[t] = *(const f16x8*)&Sh[16 * t + rlo][kc + q * 8];
#pragma unroll
        for (int c = 0; c < 2; ++c)
            b1v[c] = *(const f16x8*)(Wt1 + (size_t)(wave * 32 + 16 * c + rlo) * DIM + kc + q * 8);
        if (dual) {
            f16x8 a2v[4], b2v[2];
#pragma unroll
            for (int t = 0; t < 4; ++t) {
                int row = r0 + 16 * t + rlo;
                a2v[t] = (row < NNODE) ? *(const f16x8*)(hin + (size_t)row * DIM + kc + q * 8) : zf;
            }
#pragma unroll
            for (int c = 0; c < 2; ++c)
                b2v[c] = *(const f16x8*)(Wt2 + (size_t)(wave * 32 + 16 * c + rlo) * DIM + kc + q * 8);
#pragma unroll
            for (int t = 0; t < 4; ++t) {
                acc[t][0] = __builtin_amdgcn_mfma_f32_16x16x32_f16(a1v[t], b1v[0], acc[t][0], 0, 0, 0);
                acc[t][1] = __builtin_amdgcn_mfma_f32_16x16x32_f16(a1v[t], b1v[1], acc[t][1], 0, 0, 0);
                acc[t][0] = __builtin_amdgcn_mfma_f32_16x16x32_f16(a2v[t], b2v[0], acc[t][0], 0, 0, 0);
                acc[t][1] = __builtin_amdgcn_mfma_f32_16x16x32_f16(a2v[t], b2v[1], acc[t][1], 0, 0, 0);
            }
        } else {
#pragma unroll
            for (int t = 0; t < 4; ++t) {
                acc[t][0] = __builtin_amdgcn_mfma_f32_16x16x32_f16(a1v[t], b1v[0], acc[t][0], 0, 0, 0);
                acc[t][1] = __builtin_amdgcn_mfma_f32_16x16x32_f16(a1v[t], b1v[1], acc[t][1], 0, 0, 0);
            }
        }
    }

    const int col0 = wave * 32 + rlo, col1 = col0 + 16;
    const float bb0 = bias[col0], bb1 = bias[col1];
    float rs0 = 0, rq0 = 0, rs1 = 0, rq1 = 0;
#pragma unroll
    for (int t = 0; t < 4; ++t) {
#pragma unroll
        for (int r = 0; r < 4; ++r) {
            int row = r0 + 16 * t + q * 4 + r;
            if (row >= NNODE) continue;
            float v0 = acc[t][0][r] + bb0;
            float v1 = acc[t][1][r] + bb1;
            if (stats) { rs0 += v0; rq0 += v0 * v0; rs1 += v1; rq1 += v1 * v1; }
            C[(size_t)row * DIM + col0] = f2h(v0);
            C[(size_t)row * DIM + col1] = f2h(v1);
        }
    }
    if (stats) {
        atomicAdd(&sstat[col0], rs0);
        atomicAdd(&sstat[DIM + col0], rq0);
        atomicAdd(&sstat[col1], rs1);
        atomicAdd(&sstat[DIM + col1], rq1);
        __syncthreads();
        if (tid < DIM) {
            atomicAdd(&stats[tid], sstat[tid]);
            atomicAdd(&stats[DIM + tid], sstat[DIM + tid]);
        }
    }
}

// ---------------- plain MFMA GEMM (fp16 weights), 64x128 tile ----------------
// flags: 1=relu, 8=A f32, 32=C f16 (else f32), 64=logits epilogue, 128=batched by behavior

__global__ __launch_bounds__(256) void gemm_p(
    const void* __restrict__ Av, const u16* __restrict__ Wt,
    const float* __restrict__ bias, void* __restrict__ Cv, int M, int tiles,
    const float* __restrict__ Qf, float* __restrict__ logits, int flags) {
    int bi = 0, tile = blockIdx.x;
    if (flags & 128) { bi = blockIdx.x / tiles; tile = blockIdx.x % tiles; }
    const u16* A16 = (const u16*)Av + ((flags & 128) ? (size_t)bi * NNODE * DIM : 0);
    const float* A32 = (const float*)Av;
    const u16* W = Wt + (size_t)bi * 16384;
    const float* bs = bias + bi * DIM;
    const int r0 = tile * 64;
    const int tid = threadIdx.x;
    const int wave = tid >> 6, lane = tid & 63, q = lane >> 4, rlo = lane & 15;
    f32x4 acc[4][2];
#pragma unroll
    for (int t = 0; t < 4; ++t) { acc[t][0] = (f32x4)0.f; acc[t][1] = (f32x4)0.f; }
    const f16x8 zf = (f16x8)(f16)0.f;
#pragma unroll
    for (int kc = 0; kc < DIM; kc += 32) {
        f16x8 av[4], bv[2];
#pragma unroll
        for (int t = 0; t < 4; ++t) {
            int row = r0 + 16 * t + rlo;
            if (row < M) {
                if (flags & 8) {
                    const float* p = A32 + (size_t)row * DIM + kc + q * 8;
                    float4 x0 = *(const float4*)p;
                    float4 x1 = *(const float4*)(p + 4);
                    f16x8 tmp;
                    tmp[0] = (f16)x0.x; tmp[1] = (f16)x0.y; tmp[2] = (f16)x0.z; tmp[3] = (f16)x0.w;
                    tmp[4] = (f16)x1.x; tmp[5] = (f16)x1.y; tmp[6] = (f16)x1.z; tmp[7] = (f16)x1.w;
                    av[t] = tmp;
                } else {
                    av[t] = *(const f16x8*)(A16 + (size_t)row * DIM + kc + q * 8);
                }
            } else {
                av[t] = zf;
            }
        }
#pragma unroll
        for (int c = 0; c < 2; ++c)
            bv[c] = *(const f16x8*)(W + (size_t)(wave * 32 + 16 * c + rlo) * DIM + kc + q * 8);
#pragma unroll
        for (int t = 0; t < 4; ++t) {
            acc[t][0] = __builtin_amdgcn_mfma_f32_16x16x32_f16(av[t], bv[0], acc[t][0], 0, 0, 0);
            acc[t][1] = __builtin_amdgcn_mfma_f32_16x16x32_f16(av[t], bv[1], acc[t][1], 0, 0, 0);
        }
    }

    const int col0 = wave * 32 + rlo, col1 = col0 + 16;
    const float bb0 = bs[col0], bb1 = bs[col1];

    if (flags & 64) {
#pragma unroll
        for (int t = 0; t < 4; ++t) {
#pragma unroll
            for (int r = 0; r < 4; ++r) {
                int row = r0 + 16 * t + q * 4 + r;
                if (row < M) {
                    float v = (acc[t][0][r] + bb0) * Qf[(size_t)row * DIM + col0]
                            + (acc[t][1][r] + bb1) * Qf[(size_t)row * DIM + col1];
                    v += __shfl_xor(v, 1);
                    v += __shfl_xor(v, 2);
                    v += __shfl_xor(v, 4);
                    v += __shfl_xor(v, 8);
                    if (rlo == 0) atomicAdd(&logits[row * NB + bi], v);
                }
            }
        }
        return;
    }

#pragma unroll
    for (int t = 0; t < 4; ++t) {
#pragma unroll
        for (int r = 0; r < 4; ++r) {
            int row = r0 + 16 * t + q * 4 + r;
            if (row >= M) continue;
            float v0 = acc[t][0][r] + bb0;
            float v1 = acc[t][1][r] + bb1;
            if (flags & 1) { v0 = fmaxf(v0, 0.f); v1 = fmaxf(v1, 0.f); }
            if (flags & 32) {
                ((u16*)Cv)[(size_t)row * DIM + col0] = f2h(v0);
                ((u16*)Cv)[(size_t)row * DIM + col1] = f2h(v1);
            } else {
                ((float*)Cv)[(size_t)row * DIM + col0] = v0;
                ((float*)Cv)[(size_t)row * DIM + col1] = v1;
            }
        }
    }
}

// ---------------- BatchNorm apply: fp16 in -> fp16 out (+opt relu / residual) ----------------

__global__ __launch_bounds__(256) void bn_apply(const u16* __restrict__ h, const float* __restrict__ stats,
                                                const float* __restrict__ gamma, const float* __restrict__ beta,
                                                const u16* __restrict__ addx, u16* __restrict__ outb,
                                                int relu) {
    int t = blockIdx.x * 256 + threadIdx.x;
    if (t >= NNODE * 32) return;
    int n = t >> 5;
    int d = (t & 31) * 4;
    const float invN = 1.0f / (float)NNODE;
    float4 s = *(const float4*)&stats[d];
    float4 sq = *(const float4*)&stats[DIM + d];
    float4 g = *(const float4*)&gamma[d];
    float4 be = *(const float4*)&beta[d];
    float mx = s.x * invN, my = s.y * invN, mz = s.z * invN, mw = s.w * invN;
    float cx = g.x * rsqrtf(fmaxf(sq.x * invN - mx * mx, 0.f) + BN_EPS);
    float cy = g.y * rsqrtf(fmaxf(sq.y * invN - my * my, 0.f) + BN_EPS);
    float cz = g.z * rsqrtf(fmaxf(sq.z * invN - mz * mz, 0.f) + BN_EPS);
    float cw = g.w * rsqrtf(fmaxf(sq.w * invN - mw * mw, 0.f) + BN_EPS);
    ushort4 hv = *(const ushort4*)(h + (size_t)n * DIM + d);
    float vx = (h2f(hv.x) - mx) * cx + be.x;
    float vy = (h2f(hv.y) - my) * cy + be.y;
    float vz = (h2f(hv.z) - mz) * cz + be.z;
    float vw = (h2f(hv.w) - mw) * cw + be.w;
    if (relu) {
        vx = fmaxf(vx, 0.f); vy = fmaxf(vy, 0.f);
        vz = fmaxf(vz, 0.f); vw = fmaxf(vw, 0.f);
    }
    if (addx) {
        ushort4 u = *(const ushort4*)(addx + (size_t)n * DIM + d);
        vx += h2f(u.x); vy += h2f(u.y); vz += h2f(u.z); vw += h2f(u.w);
    }
    ushort4 o;
    o.x = f2h(vx); o.y = f2h(vy); o.z = f2h(vz); o.w = f2h(vw);
    *(ushort4*)(outb + (size_t)n * DIM + d) = o;
}

// ---------------- launch ----------------

extern "C" void kernel_launch(void* const* d_in, const int* in_sizes, int n_in,
                              void* d_out, int out_size, void* d_ws, size_t ws_size,
                              hipStream_t stream) {
    const int* edge_index    = (const int*)d_in[0];
    const int* edge_type     = (const int*)d_in[1];
    const float* item_feats  = (const float*)d_in[2];
    const float* user_emb    = (const float*)d_in[3];
    const float* user_proj_b = (const float*)d_in[5];
    const float* item_proj_b = (const float*)d_in[7];
    const float* sage_bl  = (const float*)d_in[9];
    const float* bn_gamma = (const float*)d_in[11];
    const float* bn_beta  = (const float*)d_in[12];
    const float* query_b  = (const float*)d_in[14];
    const float* key_b    = (const float*)d_in[16];
    const float* fuse_b   = (const float*)d_in[18];
    const float* refine_b = (const float*)d_in[20];
    const int E = in_sizes[1];

    const size_t ND = (size_t)NNODE * DIM;
    char* w = (char*)d_ws;
    u16* xh = (u16*)w;          w += ND * 2;              // initial x, fp16
    u16* hb = (u16*)w;          w += ND * 2;              // post-BN hidden / fused, fp16
    u16* hpre = (u16*)w;        w += ND * 2;              // pre-BN GEMM out, fp16
    u16* stackb = (u16*)w;      w += NB * ND * 2;         // per-behavior outs, fp16
    int* cnt = (int*)w;         w += (size_t)NT3P * 4;
    int* row_start = (int*)w;   w += (size_t)NT3P * 4;
    int* cur = (int*)w;         w += (size_t)NT3P * 4;
    int* adj = (int*)w;         w += (size_t)E * 4;
    float* logits = (float*)w;  w += (size_t)NNODE * NB * 4;
    u16* wt = (u16*)w;          w += (size_t)20 * 16384 * 2;
    int* bsum = (int*)w;        w += 2048;
    float* stats6 = (float*)w;  w += 6 * 256 * 4;

    const u16* wt_user = wt;
    const u16* wt_item = wt + 16384;
    const u16* wt_Wl   = wt + 2 * 16384;
    const u16* wt_Wr   = wt + 8 * 16384;
    const u16* wt_q    = wt + 14 * 16384;
    const u16* wt_key  = wt + 15 * 16384;
    const u16* wt_fuse = wt + 18 * 16384;
    const u16* wt_ref  = wt + 19 * 16384;

    float* Qf = (float*)d_out;   // d_out doubles as f32 Q buffer, then final output

    // ---- CSR build + weight conversion ----
    hipMemsetAsync(cnt, 0, (size_t)NT3P * 4, stream);
    hipMemsetAsync(logits, 0, (size_t)NNODE * NB * 4, stream);
    hipMemsetAsync(stats6, 0, 6 * 256 * 4, stream);
    int gE = (E + 255) / 256;
    count_edges<<<gE, 256, 0, stream>>>(edge_index, edge_type, E, cnt);
    scan1<<<SCAN_BLOCKS, 256, 0, stream>>>(cnt, bsum);
    scan2<<<1, 512, 0, stream>>>(bsum, SCAN_BLOCKS);
    scan3<<<SCAN_BLOCKS, 256, 0, stream>>>(cnt, bsum, row_start, cur);
    scatter_csr<<<gE, 256, 0, stream>>>(edge_index, edge_type, E, cur, adj);

    WPtrs wp;
    wp.s[0] = (const float*)d_in[4];   // user_proj_W
    wp.s[1] = (const float*)d_in[6];   // item_proj_W
    wp.s[2] = (const float*)d_in[8];   // sage_Wl
    wp.s[3] = (const float*)d_in[10];  // sage_Wr
    wp.s[4] = (const float*)d_in[13];  // query_W
    wp.s[5] = (const float*)d_in[15];  // key_W
    wp.s[6] = (const float*)d_in[17];  // fuse_W
    wp.s[7] = (const float*)d_in[19];  // refine_W
    wconv_all<<<1280, 256, 0, stream>>>(wp, wt);

    // ---- initial projection (f32 in, fp16 out) ----
    const int TU = (NUSER + 63) / 64, TI = (NITEM + 63) / 64;
    gemm_p<<<TU, 256, 0, stream>>>(user_emb, wt_user, user_proj_b, xh,
                                   NUSER, TU, nullptr, nullptr, 8 | 32);
    gemm_p<<<TI, 256, 0, stream>>>(item_feats, wt_item, item_proj_b, xh + (size_t)NUSER * DIM,
                                   NITEM, TI, nullptr, nullptr, 8 | 32);

    // ---- SAGE layers per behavior (fused gather + dual GEMM + stats) ----
    for (int b = 0; b < NB; ++b) {
        for (int l = 0; l < NL; ++l) {
            const int bl = b * NL + l;
            const u16* hin = (l == 0) ? xh : hb;
            gemm_fused<<<TILESN, 256, 0, stream>>>(
                hin, wt_Wl + (size_t)bl * 16384, sage_bl + (size_t)bl * DIM,
                wt_Wr + (size_t)bl * 16384, hpre, stats6 + bl * 256,
                adj, row_start, cnt, b, nullptr, 1);
            if (l < NL - 1)
                bn_apply<<<18750, 256, 0, stream>>>(hpre, stats6 + bl * 256,
                                                    bn_gamma + (size_t)bl * DIM,
                                                    bn_beta + (size_t)bl * DIM,
                                                    nullptr, hb, 1);
            else
                bn_apply<<<18750, 256, 0, stream>>>(hpre, stats6 + bl * 256,
                                                    bn_gamma + (size_t)bl * DIM,
                                                    bn_beta + (size_t)bl * DIM,
                                                    xh, stackb + (size_t)b * ND, 0);
        }
    }

    // ---- attention fusion ----
    gemm_p<<<TILESN, 256, 0, stream>>>(xh, wt_q, query_b, Qf,
                                       NNODE, TILESN, nullptr, nullptr, 0);       // Q -> d_out f32
    gemm_p<<<3 * TILESN, 256, 0, stream>>>(stackb, wt_key, key_b, nullptr,
                                           NNODE, TILESN, Qf, logits, 64 | 128);  // logits
    gemm_fused<<<TILESN, 256, 0, stream>>>(stackb, wt_fuse, fuse_b, nullptr,
                                           hb, nullptr, nullptr, nullptr, nullptr, 0,
                                           logits, 2);                            // fuse -> hb
    gemm_p<<<TILESN, 256, 0, stream>>>(hb, wt_ref, refine_b, d_out,
                                       NNODE, TILESN, nullptr, nullptr, 1);       // relu -> d_out
}

// Round 6
// 1286.077 us; speedup vs baseline: 9.2950x; 1.3774x over previous
//
#include <hip/hip_runtime.h>

#define NUSER 100000
#define NITEM 50000
#define NNODE 150000
#define DIM 128
#define NB 3
#define NL 2
#define BN_EPS 1e-5f
#define NT3P 450560             // 440 * 1024, padded NB*NNODE
#define SCAN_BLOCKS 440
#define TILESN 2344             // ceil(NNODE/64)
#define BNBLK 18750             // NNODE*32/256

typedef unsigned short u16;
typedef _Float16 f16;
typedef __attribute__((ext_vector_type(8))) _Float16 f16x8;
typedef __attribute__((ext_vector_type(8))) unsigned short us8;
typedef __attribute__((ext_vector_type(4))) float f32x4;

__device__ __forceinline__ float h2f(u16 u) { f16 h; __builtin_memcpy(&h, &u, 2); return (float)h; }
__device__ __forceinline__ u16 f2h(float f) { f16 h = (f16)f; u16 u; __builtin_memcpy(&u, &h, 2); return u; }

struct Out3 { u16* p[3]; };
struct WPtrs { const float* s[8]; };

// ---------------- CSR build ----------------

__global__ __launch_bounds__(256) void count_edges(const int* __restrict__ ei,
                                                   const int* __restrict__ et, int E,
                                                   int* __restrict__ cnt) {
    int t = blockIdx.x * 256 + threadIdx.x;
    if (t >= E) return;
    atomicAdd(&cnt[et[t] * NNODE + ei[E + t]], 1);
}

__global__ __launch_bounds__(256) void scan1(const int* __restrict__ cnt, int* __restrict__ bsum) {
    __shared__ int sh[256];
    int tid = threadIdx.x;
    int base = blockIdx.x * 1024 + tid * 4;
    int4 v = *(const int4*)(cnt + base);
    sh[tid] = v.x + v.y + v.z + v.w;
    __syncthreads();
    for (int off = 128; off > 0; off >>= 1) {
        if (tid < off) sh[tid] += sh[tid + off];
        __syncthreads();
    }
    if (tid == 0) bsum[blockIdx.x] = sh[0];
}

__global__ __launch_bounds__(512) void scan2(int* __restrict__ bsum, int nb) {
    __shared__ int sh[512];
    int tid = threadIdx.x;
    sh[tid] = (tid < nb) ? bsum[tid] : 0;
    __syncthreads();
    for (int off = 1; off < 512; off <<= 1) {
        int v = sh[tid];
        int add = (tid >= off) ? sh[tid - off] : 0;
        __syncthreads();
        sh[tid] = v + add;
        __syncthreads();
    }
    if (tid < nb) bsum[tid] = (tid == 0) ? 0 : sh[tid - 1];
}

__global__ __launch_bounds__(256) void scan3(const int* __restrict__ cnt, const int* __restrict__ bsum,
                                             int* __restrict__ row_start, int* __restrict__ cur) {
    __shared__ int sh[256];
    int tid = threadIdx.x;
    int base = blockIdx.x * 1024 + tid * 4;
    int4 v = *(const int4*)(cnt + base);
    sh[tid] = v.x + v.y + v.z + v.w;
    __syncthreads();
    for (int off = 1; off < 256; off <<= 1) {
        int a = sh[tid];
        int add = (tid >= off) ? sh[tid - off] : 0;
        __syncthreads();
        sh[tid] = a + add;
        __syncthreads();
    }
    int excl = ((tid == 0) ? 0 : sh[tid - 1]) + bsum[blockIdx.x];
    int4 o;
    o.x = excl; o.y = excl + v.x; o.z = o.y + v.y; o.w = o.z + v.z;
    *(int4*)(row_start + base) = o;
    *(int4*)(cur + base) = o;
}

__global__ __launch_bounds__(256) void scatter_csr(const int* __restrict__ ei,
                                                   const int* __restrict__ et, int E,
                                                   int* __restrict__ cur, int* __restrict__ adj) {
    int t = blockIdx.x * 256 + threadIdx.x;
    if (t >= E) return;
    int pos = atomicAdd(&cur[et[t] * NNODE + ei[E + t]], 1);
    adj[pos] = ei[t];
}

// ---------------- weight conversion: all 20 mats, transpose + fp16 ----------------
// mat order: 0 user, 1 item, 2..7 Wl, 8..13 Wr, 14 q, 15..17 key, 18 fuse, 19 ref

__global__ __launch_bounds__(256) void wconv_all(WPtrs w, u16* __restrict__ dst) {
    int gid = blockIdx.x * 256 + threadIdx.x;
    if (gid >= 20 * 16384) return;
    int m = gid >> 14, idx = gid & 16383;
    int k = idx & 127, n = idx >> 7;
    const float* src; int li;
    if (m == 0)       { src = w.s[0]; li = 0; }
    else if (m == 1)  { src = w.s[1]; li = 0; }
    else if (m < 8)   { src = w.s[2]; li = m - 2; }
    else if (m < 14)  { src = w.s[3]; li = m - 8; }
    else if (m == 14) { src = w.s[4]; li = 0; }
    else if (m < 18)  { src = w.s[5]; li = m - 15; }
    else if (m == 18) { src = w.s[6]; li = 0; }
    else              { src = w.s[7]; li = 0; }
    dst[(size_t)m * 16384 + idx] = f2h(src[(size_t)li * 16384 + k * 128 + n]);
}

// ---------------- SAGE layer, all 3 behaviors in one launch ----------------
// grid = 3*TILESN, b = blockIdx/TILESN. Computes pre-BN
//   h_out = mean_gather(h_in)@Wl + bl + h_in@Wr, accumulating BN stats.
// layer==1: h_in = pre-BN stackb, BN(stats_prev)+ReLU applied inline to
// gathered rows and to the A2 tile.

__global__ __launch_bounds__(256) void sage_layer(
    const u16* __restrict__ hin0, const u16* __restrict__ wt_Wl,
    const u16* __restrict__ wt_Wr, const float* __restrict__ sage_bl,
    const float* __restrict__ stats6, const float* __restrict__ gamma,
    const float* __restrict__ beta, Out3 outs, int layer,
    const int* __restrict__ adj, const int* __restrict__ row_start,
    const int* __restrict__ cnt) {
    __shared__ u16 T1[64][136];
    __shared__ u16 T2[64][136];
    __shared__ float sc[DIM];
    __shared__ float sf[DIM];
    __shared__ float sstat[256];
    const int tid = threadIdx.x;
    const int b = blockIdx.x / TILESN;
    const int tile = blockIdx.x % TILESN;
    const int r0 = tile * 64;
    const int bl = b * NL + layer;
    const u16* hin = hin0 + (layer ? (size_t)b * NNODE * DIM : 0);
    const u16* Wl = wt_Wl + (size_t)bl * 16384;
    const u16* Wr = wt_Wr + (size_t)bl * 16384;

    if (tid < DIM) {
        float scv = 1.f, sfv = 0.f;
        if (layer) {
            const int blp = b * NL;
            const float* st = stats6 + blp * 256;
            const float invN = 1.0f / (float)NNODE;
            float mu = st[tid] * invN;
            float var = fmaxf(st[DIM + tid] * invN - mu * mu, 0.f);
            scv = gamma[blp * DIM + tid] * rsqrtf(var + BN_EPS);
            sfv = beta[blp * DIM + tid] - mu * scv;
        }
        sc[tid] = scv; sf[tid] = sfv;
    }
    sstat[tid] = 0.f;
    __syncthreads();

    // stage T2: own 64 rows, BN+relu inline if layer==1
    for (int i = tid; i < 1024; i += 256) {
        int r = i >> 4, c8 = (i & 15) * 8;
        int row = r0 + r;
        us8 o;
        if (row < NNODE) {
            us8 u = *(const us8*)(hin + (size_t)row * DIM + c8);
            if (layer) {
#pragma unroll
                for (int j = 0; j < 8; ++j)
                    o[j] = f2h(fmaxf(h2f(u[j]) * sc[c8 + j] + sf[c8 + j], 0.f));
            } else {
                o = u;
            }
        } else {
            o = (us8)(u16)0;
        }
        *(us8*)&T2[r][c8] = o;
    }

    // stage T1: mean-gather, 16 lanes x 16B per row, edge-pair unroll
    {
        const int qid = tid >> 4, ql = tid & 15;
        const int c8 = ql * 8;
        float scl[8], shf[8];
#pragma unroll
        for (int j = 0; j < 8; ++j) { scl[j] = sc[c8 + j]; shf[j] = sf[c8 + j]; }
        for (int r = qid; r < 64; r += 16) {
            int n = r0 + r;
            float a[8];
#pragma unroll
            for (int j = 0; j < 8; ++j) a[j] = 0.f;
            if (n < NNODE) {
                int base = b * NNODE + n;
                int s0 = row_start[base], deg = cnt[base];
                int e = 0;
                for (; e + 1 < deg; e += 2) {
                    int s1 = adj[s0 + e], s2 = adj[s0 + e + 1];
                    us8 u1 = *(const us8*)(hin + (size_t)s1 * DIM + c8);
                    us8 u2 = *(const us8*)(hin + (size_t)s2 * DIM + c8);
                    if (layer) {
#pragma unroll
                        for (int j = 0; j < 8; ++j)
                            a[j] += fmaxf(h2f(u1[j]) * scl[j] + shf[j], 0.f)
                                  + fmaxf(h2f(u2[j]) * scl[j] + shf[j], 0.f);
                    } else {
#pragma unroll
                        for (int j = 0; j < 8; ++j) a[j] += h2f(u1[j]) + h2f(u2[j]);
                    }
                }
                if (e < deg) {
                    int s1 = adj[s0 + e];
                    us8 u1 = *(const us8*)(hin + (size_t)s1 * DIM + c8);
                    if (layer) {
#pragma unroll
                        for (int j = 0; j < 8; ++j)
                            a[j] += fmaxf(h2f(u1[j]) * scl[j] + shf[j], 0.f);
                    } else {
#pragma unroll
                        for (int j = 0; j < 8; ++j) a[j] += h2f(u1[j]);
                    }
                }
                float s = 1.0f / (float)(deg > 1 ? deg : 1);
#pragma unroll
                for (int j = 0; j < 8; ++j) a[j] *= s;
            }
            us8 o;
#pragma unroll
            for (int j = 0; j < 8; ++j) o[j] = f2h(a[j]);
            *(us8*)&T1[r][c8] = o;
        }
    }
    __syncthreads();

    // dual MFMA GEMM from LDS tiles
    const int wave = tid >> 6, lane = tid & 63, q = lane >> 4, rlo = lane & 15;
    f32x4 acc[4][2];
#pragma unroll
    for (int t = 0; t < 4; ++t) { acc[t][0] = (f32x4)0.f; acc[t][1] = (f32x4)0.f; }
#pragma unroll
    for (int kc = 0; kc < DIM; kc += 32) {
        f16x8 a1v[4], a2v[4], b1v[2], b2v[2];
#pragma unroll
        for (int t = 0; t < 4; ++t) {
            a1v[t] = *(const f16x8*)&T1[16 * t + rlo][kc + q * 8];
            a2v[t] = *(const f16x8*)&T2[16 * t + rlo][kc + q * 8];
        }
#pragma unroll
        for (int c = 0; c < 2; ++c) {
            b1v[c] = *(const f16x8*)(Wl + (size_t)(wave * 32 + 16 * c + rlo) * DIM + kc + q * 8);
            b2v[c] = *(const f16x8*)(Wr + (size_t)(wave * 32 + 16 * c + rlo) * DIM + kc + q * 8);
        }
#pragma unroll
        for (int t = 0; t < 4; ++t) {
            acc[t][0] = __builtin_amdgcn_mfma_f32_16x16x32_f16(a1v[t], b1v[0], acc[t][0], 0, 0, 0);
            acc[t][1] = __builtin_amdgcn_mfma_f32_16x16x32_f16(a1v[t], b1v[1], acc[t][1], 0, 0, 0);
            acc[t][0] = __builtin_amdgcn_mfma_f32_16x16x32_f16(a2v[t], b2v[0], acc[t][0], 0, 0, 0);
            acc[t][1] = __builtin_amdgcn_mfma_f32_16x16x32_f16(a2v[t], b2v[1], acc[t][1], 0, 0, 0);
        }
    }

    const int col0 = wave * 32 + rlo, col1 = col0 + 16;
    const float bb0 = sage_bl[bl * DIM + col0], bb1 = sage_bl[bl * DIM + col1];
    u16* C = outs.p[b];
    float rs0 = 0, rq0 = 0, rs1 = 0, rq1 = 0;
#pragma unroll
    for (int t = 0; t < 4; ++t) {
#pragma unroll
        for (int r = 0; r < 4; ++r) {
            int row = r0 + 16 * t + q * 4 + r;
            if (row >= NNODE) continue;
            float v0 = acc[t][0][r] + bb0;
            float v1 = acc[t][1][r] + bb1;
            rs0 += v0; rq0 += v0 * v0; rs1 += v1; rq1 += v1 * v1;
            C[(size_t)row * DIM + col0] = f2h(v0);
            C[(size_t)row * DIM + col1] = f2h(v1);
        }
    }
    atomicAdd(&sstat[col0], rs0);
    atomicAdd(&sstat[DIM + col0], rq0);
    atomicAdd(&sstat[col1], rs1);
    atomicAdd(&sstat[DIM + col1], rq1);
    __syncthreads();
    if (tid < DIM) {
        float* so = (float*)stats6 + bl * 256;
        atomicAdd(&so[tid], sstat[tid]);
        atomicAdd(&so[DIM + tid], sstat[DIM + tid]);
    }
}

// ---------------- final BN + residual, all 3 behaviors ----------------

__global__ __launch_bounds__(256) void bn_final(Out3 ins, const float* __restrict__ stats6,
                                                const float* __restrict__ gamma,
                                                const float* __restrict__ beta,
                                                const u16* __restrict__ xh,
                                                u16* __restrict__ stackb) {
    int blk = blockIdx.x;
    int b = blk / BNBLK;
    int t = (blk % BNBLK) * 256 + threadIdx.x;
    int n = t >> 5;
    int d = (t & 31) * 4;
    const int bl = b * NL + 1;
    const float invN = 1.0f / (float)NNODE;
    const float* st = stats6 + bl * 256;
    float4 s = *(const float4*)&st[d];
    float4 sq = *(const float4*)&st[DIM + d];
    float4 g = *(const float4*)&gamma[bl * DIM + d];
    float4 be = *(const float4*)&beta[bl * DIM + d];
    float mx = s.x * invN, my = s.y * invN, mz = s.z * invN, mw = s.w * invN;
    float cx = g.x * rsqrtf(fmaxf(sq.x * invN - mx * mx, 0.f) + BN_EPS);
    float cy = g.y * rsqrtf(fmaxf(sq.y * invN - my * my, 0.f) + BN_EPS);
    float cz = g.z * rsqrtf(fmaxf(sq.z * invN - mz * mz, 0.f) + BN_EPS);
    float cw = g.w * rsqrtf(fmaxf(sq.w * invN - mw * mw, 0.f) + BN_EPS);
    size_t off = (size_t)n * DIM + d;
    ushort4 hv = *(const ushort4*)(ins.p[b] + off);
    ushort4 xv = *(const ushort4*)(xh + off);
    ushort4 o;
    o.x = f2h((h2f(hv.x) - mx) * cx + be.x + h2f(xv.x));
    o.y = f2h((h2f(hv.y) - my) * cy + be.y + h2f(xv.y));
    o.z = f2h((h2f(hv.z) - mz) * cz + be.z + h2f(xv.z));
    o.w = f2h((h2f(hv.w) - mw) * cw + be.w + h2f(xv.w));
    *(ushort4*)(stackb + (size_t)b * NNODE * DIM + off) = o;
}

// ---------------- plain MFMA GEMM (fp16 weights), 64x128 tile ----------------
// flags: 1=relu, 8=A f32, 32=C f16 (else f32), 64=logits epilogue, 128=batched by behavior

__global__ __launch_bounds__(256) void gemm_p(
    const void* __restrict__ Av, const u16* __restrict__ Wt,
    const float* __restrict__ bias, void* __restrict__ Cv, int M, int tiles,
    const float* __restrict__ Qf, float* __restrict__ logits, int flags) {
    int bi = 0, tile = blockIdx.x;
    if (flags & 128) { bi = blockIdx.x / tiles; tile = blockIdx.x % tiles; }
    const u16* A16 = (const u16*)Av + ((flags & 128) ? (size_t)bi * NNODE * DIM : 0);
    const float* A32 = (const float*)Av;
    const u16* W = Wt + (size_t)bi * 16384;
    const float* bs = bias + bi * DIM;
    const int r0 = tile * 64;
    const int tid = threadIdx.x;
    const int wave = tid >> 6, lane = tid & 63, q = lane >> 4, rlo = lane & 15;
    f32x4 acc[4][2];
#pragma unroll
    for (int t = 0; t < 4; ++t) { acc[t][0] = (f32x4)0.f; acc[t][1] = (f32x4)0.f; }
    const f16x8 zf = (f16x8)(f16)0.f;
#pragma unroll
    for (int kc = 0; kc < DIM; kc += 32) {
        f16x8 av[4], bv[2];
#pragma unroll
        for (int t = 0; t < 4; ++t) {
            int row = r0 + 16 * t + rlo;
            if (row < M) {
                if (flags & 8) {
                    const float* p = A32 + (size_t)row * DIM + kc + q * 8;
                    float4 x0 = *(const float4*)p;
                    float4 x1 = *(const float4*)(p + 4);
                    f16x8 tmp;
                    tmp[0] = (f16)x0.x; tmp[1] = (f16)x0.y; tmp[2] = (f16)x0.z; tmp[3] = (f16)x0.w;
                    tmp[4] = (f16)x1.x; tmp[5] = (f16)x1.y; tmp[6] = (f16)x1.z; tmp[7] = (f16)x1.w;
                    av[t] = tmp;
                } else {
                    av[t] = *(const f16x8*)(A16 + (size_t)row * DIM + kc + q * 8);
                }
            } else {
                av[t] = zf;
            }
        }
#pragma unroll
        for (int c = 0; c < 2; ++c)
            bv[c] = *(const f16x8*)(W + (size_t)(wave * 32 + 16 * c + rlo) * DIM + kc + q * 8);
#pragma unroll
        for (int t = 0; t < 4; ++t) {
            acc[t][0] = __builtin_amdgcn_mfma_f32_16x16x32_f16(av[t], bv[0], acc[t][0], 0, 0, 0);
            acc[t][1] = __builtin_amdgcn_mfma_f32_16x16x32_f16(av[t], bv[1], acc[t][1], 0, 0, 0);
        }
    }

    const int col0 = wave * 32 + rlo, col1 = col0 + 16;
    const float bb0 = bs[col0], bb1 = bs[col1];

    if (flags & 64) {
#pragma unroll
        for (int t = 0; t < 4; ++t) {
#pragma unroll
            for (int r = 0; r < 4; ++r) {
                int row = r0 + 16 * t + q * 4 + r;
                if (row < M) {
                    float v = (acc[t][0][r] + bb0) * Qf[(size_t)row * DIM + col0]
                            + (acc[t][1][r] + bb1) * Qf[(size_t)row * DIM + col1];
                    v += __shfl_xor(v, 1);
                    v += __shfl_xor(v, 2);
                    v += __shfl_xor(v, 4);
                    v += __shfl_xor(v, 8);
                    if (rlo == 0) atomicAdd(&logits[row * NB + bi], v);
                }
            }
        }
        return;
    }

#pragma unroll
    for (int t = 0; t < 4; ++t) {
#pragma unroll
        for (int r = 0; r < 4; ++r) {
            int row = r0 + 16 * t + q * 4 + r;
            if (row >= M) continue;
            float v0 = acc[t][0][r] + bb0;
            float v1 = acc[t][1][r] + bb1;
            if (flags & 1) { v0 = fmaxf(v0, 0.f); v1 = fmaxf(v1, 0.f); }
            if (flags & 32) {
                ((u16*)Cv)[(size_t)row * DIM + col0] = f2h(v0);
                ((u16*)Cv)[(size_t)row * DIM + col1] = f2h(v1);
            } else {
                ((float*)Cv)[(size_t)row * DIM + col0] = v0;
                ((float*)Cv)[(size_t)row * DIM + col1] = v1;
            }
        }
    }
}

// ---------------- softmax-weighted stack sum + fuse GEMM ----------------

__global__ __launch_bounds__(256) void fuse_gemm(
    const u16* __restrict__ stk, const float* __restrict__ logits,
    const u16* __restrict__ Wt, const float* __restrict__ bias,
    u16* __restrict__ C) {
    __shared__ u16 T[64][136];
    const int tid = threadIdx.x;
    const int r0 = blockIdx.x * 64;
    for (int i = tid; i < 1024; i += 256) {
        int r = i >> 4, c8 = (i & 15) * 8;
        int n = r0 + r;
        us8 o;
        if (n < NNODE) {
            float l0 = logits[n * NB + 0];
            float l1 = logits[n * NB + 1];
            float l2 = logits[n * NB + 2];
            float mm = fmaxf(l0, fmaxf(l1, l2));
            float e0 = expf(l0 - mm), e1 = expf(l1 - mm), e2 = expf(l2 - mm);
            float inv = 1.0f / (e0 + e1 + e2);
            float w0 = e0 * inv, w1 = e1 * inv, w2 = e2 * inv;
            size_t off = (size_t)n * DIM + c8;
            us8 u0 = *(const us8*)(stk + off);
            us8 u1 = *(const us8*)(stk + (size_t)NNODE * DIM + off);
            us8 u2 = *(const us8*)(stk + (size_t)2 * NNODE * DIM + off);
#pragma unroll
            for (int j = 0; j < 8; ++j)
                o[j] = f2h(w0 * h2f(u0[j]) + w1 * h2f(u1[j]) + w2 * h2f(u2[j]));
        } else {
            o = (us8)(u16)0;
        }
        *(us8*)&T[r][c8] = o;
    }
    __syncthreads();

    const int wave = tid >> 6, lane = tid & 63, q = lane >> 4, rlo = lane & 15;
    f32x4 acc[4][2];
#pragma unroll
    for (int t = 0; t < 4; ++t) { acc[t][0] = (f32x4)0.f; acc[t][1] = (f32x4)0.f; }
#pragma unroll
    for (int kc = 0; kc < DIM; kc += 32) {
        f16x8 av[4], bv[2];
#pragma unroll
        for (int t = 0; t < 4; ++t)
            av[t] = *(const f16x8*)&T[16 * t + rlo][kc + q * 8];
#pragma unroll
        for (int c = 0; c < 2; ++c)
            bv[c] = *(const f16x8*)(Wt + (size_t)(wave * 32 + 16 * c + rlo) * DIM + kc + q * 8);
#pragma unroll
        for (int t = 0; t < 4; ++t) {
            acc[t][0] = __builtin_amdgcn_mfma_f32_16x16x32_f16(av[t], bv[0], acc[t][0], 0, 0, 0);
            acc[t][1] = __builtin_amdgcn_mfma_f32_16x16x32_f16(av[t], bv[1], acc[t][1], 0, 0, 0);
        }
    }
    const int col0 = wave * 32 + rlo, col1 = col0 + 16;
    const float bb0 = bias[col0], bb1 = bias[col1];
#pragma unroll
    for (int t = 0; t < 4; ++t) {
#pragma unroll
        for (int r = 0; r < 4; ++r) {
            int row = r0 + 16 * t + q * 4 + r;
            if (row >= NNODE) continue;
            C[(size_t)row * DIM + col0] = f2h(acc[t][0][r] + bb0);
            C[(size_t)row * DIM + col1] = f2h(acc[t][1][r] + bb1);
        }
    }
}

// ---------------- launch ----------------

extern "C" void kernel_launch(void* const* d_in, const int* in_sizes, int n_in,
                              void* d_out, int out_size, void* d_ws, size_t ws_size,
                              hipStream_t stream) {
    const int* edge_index    = (const int*)d_in[0];
    const int* edge_type     = (const int*)d_in[1];
    const float* item_feats  = (const float*)d_in[2];
    const float* user_emb    = (const float*)d_in[3];
    const float* user_proj_b = (const float*)d_in[5];
    const float* item_proj_b = (const float*)d_in[7];
    const float* sage_bl  = (const float*)d_in[9];
    const float* bn_gamma = (const float*)d_in[11];
    const float* bn_beta  = (const float*)d_in[12];
    const float* query_b  = (const float*)d_in[14];
    const float* key_b    = (const float*)d_in[16];
    const float* fuse_b   = (const float*)d_in[18];
    const float* refine_b = (const float*)d_in[20];
    const int E = in_sizes[1];

    const size_t ND = (size_t)NNODE * DIM;
    char* w = (char*)d_ws;
    u16* xh = (u16*)w;          w += ND * 2;              // initial x, fp16
    u16* stackb = (u16*)w;      w += NB * ND * 2;         // pre-BN l0 h, then final outs
    u16* fbuf = (u16*)w;        w += ND * 2;              // hpre slice 0 / fused
    int* cnt = (int*)w;         w += (size_t)NT3P * 4;
    int* row_start = (int*)w;   w += (size_t)NT3P * 4;
    int* cur = (int*)w;         w += (size_t)NT3P * 4;
    int* adj = (int*)w;         w += (size_t)E * 4;
    float* logits = (float*)w;  w += (size_t)NNODE * NB * 4;
    u16* wt = (u16*)w;          w += (size_t)20 * 16384 * 2;
    int* bsum = (int*)w;        w += 2048;
    float* stats6 = (float*)w;  w += 6 * 256 * 4;

    const u16* wt_user = wt;
    const u16* wt_item = wt + 16384;
    const u16* wt_Wl   = wt + 2 * 16384;
    const u16* wt_Wr   = wt + 8 * 16384;
    const u16* wt_q    = wt + 14 * 16384;
    const u16* wt_key  = wt + 15 * 16384;
    const u16* wt_fuse = wt + 18 * 16384;
    const u16* wt_ref  = wt + 19 * 16384;

    u16* dout16 = (u16*)d_out;   // during SAGE: hpre slices 1,2; later Qf f32 / final out
    float* Qf = (float*)d_out;

    // ---- CSR build + weight conversion ----
    hipMemsetAsync(cnt, 0, (size_t)NT3P * 4, stream);
    hipMemsetAsync(logits, 0, (size_t)NNODE * NB * 4, stream);
    hipMemsetAsync(stats6, 0, 6 * 256 * 4, stream);
    int gE = (E + 255) / 256;
    count_edges<<<gE, 256, 0, stream>>>(edge_index, edge_type, E, cnt);
    scan1<<<SCAN_BLOCKS, 256, 0, stream>>>(cnt, bsum);
    scan2<<<1, 512, 0, stream>>>(bsum, SCAN_BLOCKS);
    scan3<<<SCAN_BLOCKS, 256, 0, stream>>>(cnt, bsum, row_start, cur);
    scatter_csr<<<gE, 256, 0, stream>>>(edge_index, edge_type, E, cur, adj);

    WPtrs wp;
    wp.s[0] = (const float*)d_in[4];
    wp.s[1] = (const float*)d_in[6];
    wp.s[2] = (const float*)d_in[8];
    wp.s[3] = (const float*)d_in[10];
    wp.s[4] = (const float*)d_in[13];
    wp.s[5] = (const float*)d_in[15];
    wp.s[6] = (const float*)d_in[17];
    wp.s[7] = (const float*)d_in[19];
    wconv_all<<<1280, 256, 0, stream>>>(wp, wt);

    // ---- initial projection (f32 in, fp16 out) ----
    const int TU = (NUSER + 63) / 64, TI = (NITEM + 63) / 64;
    gemm_p<<<TU, 256, 0, stream>>>(user_emb, wt_user, user_proj_b, xh,
                                   NUSER, TU, nullptr, nullptr, 8 | 32);
    gemm_p<<<TI, 256, 0, stream>>>(item_feats, wt_item, item_proj_b, xh + (size_t)NUSER * DIM,
                                   NITEM, TI, nullptr, nullptr, 8 | 32);

    // ---- SAGE: 3 launches for the whole stack ----
    Out3 out_l0, out_l1;
    for (int b = 0; b < NB; ++b) out_l0.p[b] = stackb + (size_t)b * ND;
    out_l1.p[0] = fbuf;
    out_l1.p[1] = dout16;
    out_l1.p[2] = dout16 + ND;

    sage_layer<<<NB * TILESN, 256, 0, stream>>>(xh, wt_Wl, wt_Wr, sage_bl,
                                                stats6, bn_gamma, bn_beta,
                                                out_l0, 0, adj, row_start, cnt);
    sage_layer<<<NB * TILESN, 256, 0, stream>>>(stackb, wt_Wl, wt_Wr, sage_bl,
                                                stats6, bn_gamma, bn_beta,
                                                out_l1, 1, adj, row_start, cnt);
    bn_final<<<NB * BNBLK, 256, 0, stream>>>(out_l1, stats6, bn_gamma, bn_beta,
                                             xh, stackb);

    // ---- attention fusion ----
    gemm_p<<<TILESN, 256, 0, stream>>>(xh, wt_q, query_b, Qf,
                                       NNODE, TILESN, nullptr, nullptr, 0);       // Q -> d_out f32
    gemm_p<<<NB * TILESN, 256, 0, stream>>>(stackb, wt_key, key_b, nullptr,
                                            NNODE, TILESN, Qf, logits, 64 | 128); // logits
    fuse_gemm<<<TILESN, 256, 0, stream>>>(stackb, logits, wt_fuse, fuse_b, fbuf); // fused -> fbuf
    gemm_p<<<TILESN, 256, 0, stream>>>(fbuf, wt_ref, refine_b, d_out,
                                       NNODE, TILESN, nullptr, nullptr, 1);       // relu -> d_out
}